// Round 2
// baseline (1906.504 us; speedup 1.0000x reference)
//
#include <hip/hip_runtime.h>
#include <math.h>

// LDGCNN forward: 4 EdgeConv blocks (knn K=20) + 1x1 conv block + global max pool + 3 FC.
// B=8, N=2048. Feature buffer X: (B, N, XS) rows, columns [pts(3)|f1(64)|f2(64)|f3(64)|f4(128)].
// XS=324 keeps rows 16B-aligned for float4 loads (column 323 is an unused pad).

constexpr int BB = 8;
constexpr int NN = 2048;
constexpr int KK = 20;
constexpr int CT = 323;
constexpr int XS = 324;
constexpr float NEGS = 0.2f;

__device__ __forceinline__ float lrelu(float v) { return v > 0.0f ? v : NEGS * v; }

__device__ __forceinline__ void atomicMaxF(float* addr, float v) {
    if (v >= 0.0f) atomicMax((int*)addr, __float_as_int(v));
    else           atomicMin((unsigned int*)addr, __float_as_uint(v));
}

// ---- fused prep: weight packs + W5T transpose + gfeat init + transpose/sq0 + X zero-fill -
// Wa4/Wd4 packed layout, per-stage chunk-row base (float4 elems): st0@0, st1@64, st2@1216
// (36 chunks: 34 real + 2 zero-padded so stage-3 NPASS=6 divides evenly), st3@3520.
// Zero-padded chunks + zero-filled X feature columns make pad reads exactly 0*0.
constexpr int WTOT = 9920;
__global__ void k_prep_all(const float* __restrict__ W1, const float* __restrict__ W2,
                           const float* __restrict__ W3, const float* __restrict__ W4,
                           const float* __restrict__ W5, const float* __restrict__ x,
                           float4* __restrict__ Wa4, float4* __restrict__ Wd4,
                           float* __restrict__ W5T, float* __restrict__ gfeat,
                           float* __restrict__ X, float* __restrict__ sq) {
    int j = blockIdx.x * blockDim.x + threadIdx.x;
    if (j < WTOT) {
        int base, Cout, C;
        const float* W;
        if (j < 64)        { base = 0;    Cout = 64;  C = 3;   W = W1; }
        else if (j < 1216) { base = 64;   Cout = 64;  C = 67;  W = W2; }
        else if (j < 3520) { base = 1216; Cout = 64;  C = 131; W = W3; }
        else               { base = 3520; Cout = 128; C = 195; W = W4; }
        int local = j - base;
        int chunk = local / Cout, o = local % Cout;
        float wa[4], wd[4];
#pragma unroll
        for (int i = 0; i < 4; ++i) {
            int c = 4 * chunk + i;
            if (c < C) {
                wa[i] = W[(size_t)o * 2 * C + c];
                wd[i] = W[(size_t)o * 2 * C + C + c] - wa[i];
            } else { wa[i] = 0.f; wd[i] = 0.f; }
        }
        Wa4[j] = make_float4(wa[0], wa[1], wa[2], wa[3]);
        Wd4[j] = make_float4(wd[0], wd[1], wd[2], wd[3]);
    } else if (j < WTOT + XS * 1024) {
        int t = j - WTOT;
        int c = t / 1024, o = t % 1024;
        W5T[t] = (c < CT) ? W5[(size_t)o * CT + c] : 0.f;   // row 323 zeroed
    } else if (j < WTOT + XS * 1024 + BB * 1024) {
        gfeat[j - WTOT - XS * 1024] = -INFINITY;
    } else if (j < WTOT + XS * 1024 + BB * 1024 + BB * NN) {
        int i = j - WTOT - XS * 1024 - BB * 1024;            // b*NN + n
        int b = i >> 11, n = i & 2047;
        const float* xb = x + (size_t)b * 3 * NN;
        float vx = xb[n], vy = xb[NN + n], vz = xb[2 * NN + n];
        float* row = X + (size_t)i * XS;
        row[0] = vx; row[1] = vy; row[2] = vz; row[3] = 0.f;
        sq[i] = vx * vx + vy * vy + vz * vz;
    } else if (j < WTOT + XS * 1024 + BB * 1024 + BB * NN + BB * NN * 80) {
        // zero-fill X feature columns (float4 indices 1..80 of each row; col 3 done above)
        int t = j - (WTOT + XS * 1024 + BB * 1024 + BB * NN);
        int row = t / 80, c4 = 1 + (t - 80 * row);
        ((float4*)X)[(size_t)row * (XS / 4) + c4] = make_float4(0.f, 0.f, 0.f, 0.f);
    }
}

// ---- dist[b][n][m] = max(sq_n + sq_m - 2*dot, 0) — SYMMETRIC: only tiles ti>=tj ----------
// 128x128 tile, 8x8 per thread. Off-diagonal blocks write direct + mirrored (LDS transpose).
constexpr int TM = 128;
__global__ __launch_bounds__(256) void k_dist(const float* __restrict__ X,
                                              const float* __restrict__ sq,
                                              float* __restrict__ dist, int C) {
    int b = blockIdx.z;
    int blk = blockIdx.x;                 // 0..135 -> (ti, tj), ti >= tj
    int ti = (int)((sqrtf(8.0f * blk + 1.0f) - 1.0f) * 0.5f);
    while ((ti + 1) * (ti + 2) / 2 <= blk) ++ti;
    while (ti * (ti + 1) / 2 > blk) --ti;
    int tj = blk - ti * (ti + 1) / 2;
    int m0 = ti * TM;                     // col tile
    int n0 = tj * TM;                     // row tile
    __shared__ float smem[4352];          // 17 KB: staging (16 KB) / transpose T[32][129]
    float* AsB = smem;                    // As[16][TM]
    float* BsB = smem + 2048;             // Bs[16][TM]
    int tid = threadIdx.x;
    int tx = tid & 15;        // cols: m0 + tx + 16*j
    int ty = tid >> 4;        // rows: n0 + ty*8 + i
    float acc[8][8] = {};
    const float* Xb = X + (size_t)b * NN * XS;
    int sr = tid & 127;       // staging row
    int sc0 = (tid >> 7) * 8; // staging channel half (0 or 8)
    for (int c0 = 0; c0 < C; c0 += 16) {
        const float* arow = Xb + (size_t)(n0 + sr) * XS + c0 + sc0;
        const float* brow = Xb + (size_t)(m0 + sr) * XS + c0 + sc0;
        float4 a0 = *(const float4*)(arow);
        float4 a1 = *(const float4*)(arow + 4);
        float4 b0 = *(const float4*)(brow);
        float4 b1 = *(const float4*)(brow + 4);
        float av[8] = {a0.x, a0.y, a0.z, a0.w, a1.x, a1.y, a1.z, a1.w};
        float bv8[8] = {b0.x, b0.y, b0.z, b0.w, b1.x, b1.y, b1.z, b1.w};
#pragma unroll
        for (int i = 0; i < 8; ++i) {
            bool inr = (c0 + sc0 + i) < C;
            AsB[(sc0 + i) * TM + sr] = inr ? av[i] : 0.f;
            BsB[(sc0 + i) * TM + sr] = inr ? bv8[i] : 0.f;
        }
        __syncthreads();
#pragma unroll
        for (int cc = 0; cc < 16; ++cc) {
            float4 a0r = *(const float4*)&AsB[cc * TM + ty * 8];
            float4 a1r = *(const float4*)&AsB[cc * TM + ty * 8 + 4];
            float a[8] = {a0r.x, a0r.y, a0r.z, a0r.w, a1r.x, a1r.y, a1r.z, a1r.w};
            float bv[8];
#pragma unroll
            for (int j = 0; j < 8; ++j) bv[j] = BsB[cc * TM + tx + 16 * j];
#pragma unroll
            for (int i = 0; i < 8; ++i)
#pragma unroll
                for (int j = 0; j < 8; ++j)
                    acc[i][j] = fmaf(a[i], bv[j], acc[i][j]);
        }
        __syncthreads();
    }
    const float* sqb = sq + b * NN;
    float* db = dist + (size_t)b * NN * NN;
    float sm[8];
#pragma unroll
    for (int j = 0; j < 8; ++j) sm[j] = sqb[m0 + tx + 16 * j];
#pragma unroll
    for (int i = 0; i < 8; ++i) {
        int n = n0 + ty * 8 + i;
        float sn = sqb[n];
#pragma unroll
        for (int j = 0; j < 8; ++j) {
            float d = fmaxf(sn + sm[j] - 2.f * acc[i][j], 0.f);
            acc[i][j] = d;                                   // keep for mirror
            db[(size_t)n * NN + m0 + tx + 16 * j] = d;
        }
    }
    if (ti != tj) {
        // mirrored tile: rows m0.., cols n0.. — 4 passes of 32 m-rows via LDS transpose
        float* T = smem;                  // [32][129]
        int r = tid >> 3;                 // 0..31
        int c0 = (tid & 7) * 16;          // 0..112
#pragma unroll
        for (int p = 0; p < 4; ++p) {
            __syncthreads();              // protect staging/previous pass reads
#pragma unroll
            for (int jj = 0; jj < 2; ++jj) {
                int j = 2 * p + jj;       // m_local = 32p + tx + 16jj
#pragma unroll
                for (int i = 0; i < 8; ++i)
                    T[(tx + 16 * jj) * 129 + ty * 8 + i] = acc[i][j];
            }
            __syncthreads();
            float v[16];
#pragma unroll
            for (int k = 0; k < 16; ++k) v[k] = T[r * 129 + c0 + k];
            float* dst = db + (size_t)(m0 + 32 * p + r) * NN + n0 + c0;
#pragma unroll
            for (int k = 0; k < 4; ++k)
                *(float4*)(dst + 4 * k) = make_float4(v[4 * k], v[4 * k + 1],
                                                      v[4 * k + 2], v[4 * k + 3]);
        }
    }
}

// ---- Batcher odd-even mergesort network, N=16, fully unrolled (registers) ----------------
__device__ __forceinline__ void sortnet16(unsigned long long* k) {
#pragma unroll
    for (int p = 1; p < 16; p <<= 1) {
#pragma unroll
        for (int q = p; q >= 1; q >>= 1) {
#pragma unroll
            for (int j = q % p; j + q < 16; j += 2 * q) {
#pragma unroll
                for (int i = 0; i < q; ++i) {
                    int a = j + i, bx = j + i + q;
                    if (bx < 16 && (a / (2 * p)) == (bx / (2 * p))) {
                        unsigned long long ka = k[a], kb = k[bx];
                        bool sw = kb < ka;
                        k[a]  = sw ? kb : ka;
                        k[bx] = sw ? ka : kb;
                    }
                }
            }
        }
    }
}

// ---- top-K smallest per row: key = (bits(d)<<11)|m; ties -> lower m (lax.top_k) ----------
__global__ __launch_bounds__(128) void k_select(const float* __restrict__ dist,
                                                int* __restrict__ idx) {
    int bn = blockIdx.x;   // b*NN + n
    int tid = threadIdx.x;
    int wv = tid >> 6;
    int lane = tid & 63;
    const float* drow = dist + (size_t)bn * NN;
    int m0 = wv * 1024 + lane * 16;
    unsigned long long k[16];
#pragma unroll
    for (int i = 0; i < 4; ++i) {
        float4 v = *(const float4*)(drow + m0 + 4 * i);
        k[4 * i + 0] = ((unsigned long long)__float_as_uint(v.x) << 11) | (unsigned)(m0 + 4 * i + 0);
        k[4 * i + 1] = ((unsigned long long)__float_as_uint(v.y) << 11) | (unsigned)(m0 + 4 * i + 1);
        k[4 * i + 2] = ((unsigned long long)__float_as_uint(v.z) << 11) | (unsigned)(m0 + 4 * i + 2);
        k[4 * i + 3] = ((unsigned long long)__float_as_uint(v.w) << 11) | (unsigned)(m0 + 4 * i + 3);
    }
    sortnet16(k);
    __shared__ unsigned long long wl[2 * KK];
    for (int kk = 0; kk < KK; ++kk) {
        unsigned long long g = k[0];
#pragma unroll
        for (int s = 1; s < 64; s <<= 1) {
            unsigned long long o = (unsigned long long)__shfl_xor((long long)g, s, 64);
            if (o < g) g = o;
        }
        bool win = (k[0] == g);
#pragma unroll
        for (int i = 0; i < 15; ++i) k[i] = win ? k[i + 1] : k[i];
        k[15] = win ? ~0ull : k[15];
        if (lane == 0) wl[wv * KK + kk] = g;
    }
    __syncthreads();
    if (wv == 0) {
        unsigned long long mk = (lane < 2 * KK) ? wl[lane] : ~0ull;
        int* orow = idx + (size_t)bn * KK;
        for (int kk = 0; kk < KK; ++kk) {
            unsigned long long g = mk;
#pragma unroll
            for (int s = 1; s < 64; s <<= 1) {
                unsigned long long o = (unsigned long long)__shfl_xor((long long)g, s, 64);
                if (o < g) g = o;
            }
            if (mk == g) mk = ~0ull;
            if (lane == 0) orow[kk] = (int)(g & 2047u);
        }
    }
}

// ---- EdgeConv: P points/block, MO outputs/thread, NPASS channel passes. ------------------
// R14: kernel is LDS-read-pipe bound (broadcast ds_read_b128 delivers only 16B). LDS read
// instrs per point = 21*(COUT/MO)/64 per chunk, so MO=4 halves them vs MO=2.
// R15 post-mortem: MO=4 at 128/64-thread blocks collapsed occupancy (18.5%) and regressed;
// this version keeps NTHR=256 everywhere (P=16 for COUT=64, P=8 for COUT=128) and uses more
// NPASS so LDS/block stays <=34KB (>=4 blocks/CU). __launch_bounds__(256,4) caps VGPR at 128
// (R1 measured 108 for this inner loop -> no spill). Stage-3 NC4 padded 34->36 (zero weights
// + zero-filled X columns keep pad contributions exactly 0).
// PSTR pads per-point nbr stride to ==2 mod 8 float4s so the up-to-4 distinct broadcast
// addresses per wave land 8 banks apart (conflict-free).
// Epilogue updates sq[bn] += sum(new channels^2) via width-OS shuffle reduction.
template <int NC4, int COUT, int P, int NPASS, int MO>
__global__ __launch_bounds__(P * COUT / MO, 4)
void k_conv(const float* __restrict__ X, const int* __restrict__ idx,
            const float4* __restrict__ Wa4, const float4* __restrict__ Wd4,
            const float* __restrict__ scale, const float* __restrict__ bias,
            int outoff, float* __restrict__ Xout, float* __restrict__ sq) {
    constexpr int NCP = NC4 / NPASS;      // chunks per pass (exact: 1, 6, 6, 10)
    constexpr int OS = COUT / MO;         // output slots per point (threads per point)
    constexpr int NTHR = P * OS;
    constexpr int PSTR = KK * NCP + (((2 - (KK * NCP) % 8) + 8) % 8);  // ≡2 mod 8
    int bn0 = blockIdx.x * P;             // P consecutive points, same batch
    int b = bn0 >> 11;                    // NN = 2048
    __shared__ float4 ctr4[P * NCP];
    __shared__ float4 nbr4[P * PSTR];
    __shared__ int sIdx[P * KK];
    int tid = threadIdx.x;
    for (int j = tid; j < P * KK; j += NTHR) sIdx[j] = idx[(size_t)bn0 * KK + j];
    __syncthreads();
    int o = tid & (OS - 1);
    int p = tid / OS;
    float bacc[MO];
    float acc[MO][KK];
#pragma unroll
    for (int m = 0; m < MO; ++m) {
        bacc[m] = 0.f;
#pragma unroll
        for (int kk = 0; kk < KK; ++kk) acc[m][kk] = 0.f;
    }
#pragma unroll 1
    for (int q = 0; q < NPASS; ++q) {
        int cbase = q * NCP;              // global chunk base for this pass
        // stage ctr chunks
        for (int j = tid; j < P * NCP; j += NTHR) {
            int pp = j / NCP, c = j - pp * NCP;
            ctr4[j] = *(const float4*)(X + (size_t)(bn0 + pp) * XS + 4 * (cbase + c));
        }
        // stage nbr chunks (padded per-point stride PSTR)
        for (int j = tid; j < P * KK * NCP; j += NTHR) {
            int pk = j / NCP, c = j - pk * NCP;
            int pp = pk / KK, kk = pk - pp * KK;
            nbr4[pp * PSTR + kk * NCP + c] =
                *(const float4*)(X + (size_t)(b * NN + sIdx[pk]) * XS + 4 * (cbase + c));
        }
        __syncthreads();
        const float4* cp = ctr4 + p * NCP;
        const float4* np = nbr4 + p * PSTR;
#pragma unroll 2
        for (int ch = 0; ch < NCP; ++ch) {
            int gch = cbase + ch;
            float4 wa[MO], wd[MO];
#pragma unroll
            for (int m = 0; m < MO; ++m) {
                wa[m] = Wa4[(size_t)gch * COUT + o + m * OS];
                wd[m] = Wd4[(size_t)gch * COUT + o + m * OS];
            }
            float4 cv = cp[ch];
#pragma unroll
            for (int m = 0; m < MO; ++m) {
                bacc[m] = fmaf(cv.x, wd[m].x, bacc[m]);
                bacc[m] = fmaf(cv.y, wd[m].y, bacc[m]);
                bacc[m] = fmaf(cv.z, wd[m].z, bacc[m]);
                bacc[m] = fmaf(cv.w, wd[m].w, bacc[m]);
            }
#pragma unroll
            for (int kk = 0; kk < KK; ++kk) {
                float4 nv = np[kk * NCP + ch];
#pragma unroll
                for (int m = 0; m < MO; ++m) {
                    acc[m][kk] = fmaf(nv.x, wa[m].x, acc[m][kk]);
                    acc[m][kk] = fmaf(nv.y, wa[m].y, acc[m][kk]);
                    acc[m][kk] = fmaf(nv.z, wa[m].z, acc[m][kk]);
                    acc[m][kk] = fmaf(nv.w, wa[m].w, acc[m][kk]);
                }
            }
        }
        if (q + 1 < NPASS) __syncthreads();   // before next pass overwrites LDS
    }
    float* orow = Xout + (size_t)(bn0 + p) * XS + outoff;
    float v = 0.f;
#pragma unroll
    for (int m = 0; m < MO; ++m) {
        float s0 = scale[o + m * OS], bi0 = bias[o + m * OS];
        float mx = -INFINITY;
#pragma unroll
        for (int kk = 0; kk < KK; ++kk)
            mx = fmaxf(mx, lrelu((bacc[m] + acc[m][kk]) * s0 + bi0));
        orow[o + m * OS] = mx;
        v = fmaf(mx, mx, v);
    }
    // fused sq update for next stage: sq += sum over new channels of value^2
#pragma unroll
    for (int s = 1; s < OS; s <<= 1) v += __shfl_xor(v, s, OS);
    if (o == 0) sq[bn0 + p] += v;
}

// ---- block5: g = lrelu((X . W5^T)*s5+b5), atomic max over n into gfeat -------------------
// float4 LDS broadcasts (8 b128 per 128 FMAs, 1:16) instead of scalar b32.
constexpr int RB = 8;
constexpr int X4S = XS / 4;   // 81 float4 per row
__global__ __launch_bounds__(256) void k_stage5(const float* __restrict__ X,
                                                const float* __restrict__ W5T,
                                                const float* __restrict__ s5,
                                                const float* __restrict__ b5,
                                                float* __restrict__ gfeat) {
    int blk = blockIdx.x;
    int b = blk / (NN / RB);
    int n0 = (blk % (NN / RB)) * RB;
    __shared__ float4 rows4[RB][X4S];
    int tid = threadIdx.x;
    const float4* X4 = (const float4*)X;
    for (int j = tid; j < RB * X4S; j += 256) {
        int r = j / X4S, c = j - r * X4S;
        rows4[r][c] = X4[(size_t)(b * NN + n0 + r) * X4S + c];
    }
    __syncthreads();
    const float4* W5T4 = (const float4*)W5T;   // [XS][256] float4 per row
    float acc[RB][4] = {};
    for (int c4 = 0; c4 < X4S; ++c4) {
        float4 w0 = W5T4[(size_t)(4 * c4 + 0) * 256 + tid];
        float4 w1 = W5T4[(size_t)(4 * c4 + 1) * 256 + tid];
        float4 w2 = W5T4[(size_t)(4 * c4 + 2) * 256 + tid];
        float4 w3 = W5T4[(size_t)(4 * c4 + 3) * 256 + tid];
#pragma unroll
        for (int r = 0; r < RB; ++r) {
            float4 a = rows4[r][c4];
            acc[r][0] = fmaf(a.x, w0.x, acc[r][0]);
            acc[r][1] = fmaf(a.x, w0.y, acc[r][1]);
            acc[r][2] = fmaf(a.x, w0.z, acc[r][2]);
            acc[r][3] = fmaf(a.x, w0.w, acc[r][3]);
            acc[r][0] = fmaf(a.y, w1.x, acc[r][0]);
            acc[r][1] = fmaf(a.y, w1.y, acc[r][1]);
            acc[r][2] = fmaf(a.y, w1.z, acc[r][2]);
            acc[r][3] = fmaf(a.y, w1.w, acc[r][3]);
            acc[r][0] = fmaf(a.z, w2.x, acc[r][0]);
            acc[r][1] = fmaf(a.z, w2.y, acc[r][1]);
            acc[r][2] = fmaf(a.z, w2.z, acc[r][2]);
            acc[r][3] = fmaf(a.z, w2.w, acc[r][3]);
            acc[r][0] = fmaf(a.w, w3.x, acc[r][0]);
            acc[r][1] = fmaf(a.w, w3.y, acc[r][1]);
            acc[r][2] = fmaf(a.w, w3.z, acc[r][2]);
            acc[r][3] = fmaf(a.w, w3.w, acc[r][3]);
        }
    }
    int o0 = tid * 4;
#pragma unroll
    for (int i = 0; i < 4; ++i) {
        int o = o0 + i;
        float s = s5[o], bbv = b5[o];
        float mx = -INFINITY;
#pragma unroll
        for (int r = 0; r < RB; ++r) {
            float v = lrelu(acc[r][i] * s + bbv);
            mx = fmaxf(v, mx);
        }
        atomicMaxF(&gfeat[b * 1024 + o], mx);
    }
}

// ---- fused FC head: fc1 -> fc2 -> fc3 per batch row, intermediates in LDS ----------------
__global__ __launch_bounds__(256) void k_fc(const float* __restrict__ gfeat,
                                            const float* __restrict__ fW1, const float* __restrict__ fb1,
                                            const float* __restrict__ fs1, const float* __restrict__ fB1,
                                            const float* __restrict__ fW2, const float* __restrict__ fb2,
                                            const float* __restrict__ fs2, const float* __restrict__ fB2,
                                            const float* __restrict__ fW3, const float* __restrict__ fb3,
                                            float* __restrict__ logits) {
    int b = blockIdx.x;
    __shared__ float g[1024];
    __shared__ float h1s[512];
    __shared__ float h2s[256];
    int tid = threadIdx.x;
    for (int j = tid; j < 1024; j += 256) g[j] = gfeat[b * 1024 + j];
    __syncthreads();
    for (int o = tid; o < 512; o += 256) {
        const float* wr = fW1 + (size_t)o * 1024;
        float acc = 0.f;
        for (int c = 0; c < 1024; ++c) acc = fmaf(g[c], wr[c], acc);
        h1s[o] = lrelu((acc + fb1[o]) * fs1[o] + fB1[o]);
    }
    __syncthreads();
    {
        int o = tid;
        const float* wr = fW2 + (size_t)o * 512;
        float acc = 0.f;
        for (int c = 0; c < 512; ++c) acc = fmaf(h1s[c], wr[c], acc);
        h2s[o] = lrelu((acc + fb2[o]) * fs2[o] + fB2[o]);
    }
    __syncthreads();
    if (tid < 40) {
        const float* wr = fW3 + (size_t)tid * 256;
        float acc = 0.f;
        for (int c = 0; c < 256; ++c) acc = fmaf(h2s[c], wr[c], acc);
        logits[b * 40 + tid] = acc + fb3[tid];
    }
}

extern "C" void kernel_launch(void* const* d_in, const int* in_sizes, int n_in,
                              void* d_out, int out_size, void* d_ws, size_t ws_size,
                              hipStream_t stream) {
    const float* x   = (const float*)d_in[0];
    const float* W1  = (const float*)d_in[1];
    const float* s1  = (const float*)d_in[2];
    const float* b1  = (const float*)d_in[3];
    const float* W2  = (const float*)d_in[4];
    const float* s2  = (const float*)d_in[5];
    const float* b2  = (const float*)d_in[6];
    const float* W3  = (const float*)d_in[7];
    const float* s3  = (const float*)d_in[8];
    const float* b3  = (const float*)d_in[9];
    const float* W4  = (const float*)d_in[10];
    const float* s4  = (const float*)d_in[11];
    const float* b4  = (const float*)d_in[12];
    const float* W5  = (const float*)d_in[13];
    const float* s5  = (const float*)d_in[14];
    const float* b5  = (const float*)d_in[15];
    const float* fW1 = (const float*)d_in[16];
    const float* fb1 = (const float*)d_in[17];
    const float* fs1 = (const float*)d_in[18];
    const float* fB1 = (const float*)d_in[19];
    const float* fW2 = (const float*)d_in[20];
    const float* fb2 = (const float*)d_in[21];
    const float* fs2 = (const float*)d_in[22];
    const float* fB2 = (const float*)d_in[23];
    const float* fW3 = (const float*)d_in[24];
    const float* fb3 = (const float*)d_in[25];

    float* out    = (float*)d_out;
    float* logits = out;          // 8*40
    float* gfeat  = out + 320;    // 8*1024

    char* ws = (char*)d_ws;
    size_t off = 0;
    auto alloc = [&](size_t bytes) -> void* {
        void* p = ws + off;
        off += (bytes + 255) & ~(size_t)255;
        return p;
    };
    float* X    = (float*)alloc((size_t)BB * NN * XS * 4);      // 21.2 MB
    float* sq   = (float*)alloc((size_t)BB * NN * 4);
    float* dist = (float*)alloc((size_t)BB * NN * NN * 4);      // 134 MB
    int*   idx  = (int*)  alloc((size_t)BB * NN * KK * 4);
    float4* Wa4 = (float4*)alloc((size_t)WTOT * 16);
    float4* Wd4 = (float4*)alloc((size_t)WTOT * 16);
    float* W5T  = (float*)alloc((size_t)XS * 1024 * 4);
    (void)ws_size; (void)in_sizes; (void)n_in; (void)out_size;

    // one-shot prep: weight packs + W5T + gfeat init + transpose/sq0 + X zero-fill
    int prepTot = WTOT + XS * 1024 + BB * 1024 + BB * NN + BB * NN * 80;
    k_prep_all<<<(prepTot + 255) / 256, 256, 0, stream>>>(W1, W2, W3, W4, W5, x,
                                                          Wa4, Wd4, W5T, gfeat, X, sq);

    const int Cs[4]    = {3, 67, 131, 195};
    const int offs[4]  = {3, 67, 131, 195};
    const int WOFF[4]  = {0, 64, 1216, 3520};   // chunk-row base in packed Wa4/Wd4
    const float* ss[4] = {s1, s2, s3, s4};
    const float* bs[4] = {b1, b2, b3, b4};

    constexpr int NT = NN / TM;                 // 16 tiles per dim
    constexpr int NBLK = NT * (NT + 1) / 2;     // 136 lower-triangle tiles
    for (int st = 0; st < 4; ++st) {
        int C = Cs[st];
        dim3 dg(NBLK, 1, BB);
        k_dist<<<dg, 256, 0, stream>>>(X, sq, dist, C);
        k_select<<<BB * NN, 128, 0, stream>>>(dist, idx);
        const float4* wa = Wa4 + WOFF[st];
        const float4* wd = Wd4 + WOFF[st];
        switch (st) {
            case 0: k_conv<1,  64, 16, 1, 4><<<BB * NN / 16, 256, 0, stream>>>(X, idx, wa, wd, ss[st], bs[st], offs[st], X, sq); break;
            case 1: k_conv<18, 64, 16, 3, 4><<<BB * NN / 16, 256, 0, stream>>>(X, idx, wa, wd, ss[st], bs[st], offs[st], X, sq); break;
            case 2: k_conv<36, 64, 16, 6, 4><<<BB * NN / 16, 256, 0, stream>>>(X, idx, wa, wd, ss[st], bs[st], offs[st], X, sq); break;
            case 3: k_conv<50, 128, 8, 5, 4><<<BB * NN / 8,  256, 0, stream>>>(X, idx, wa, wd, ss[st], bs[st], offs[st], X, sq); break;
        }
    }

    k_stage5<<<BB * (NN / RB), 256, 0, stream>>>(X, W5T, s5, b5, gfeat);
    k_fc<<<BB, 256, 0, stream>>>(gfeat, fW1, fb1, fs1, fB1,
                                 fW2, fb2, fs2, fB2, fW3, fb3, logits);
}

// Round 3
// 1753.960 us; speedup vs baseline: 1.0870x; 1.0870x over previous
//
#include <hip/hip_runtime.h>
#include <math.h>

// LDGCNN forward: 4 EdgeConv blocks (knn K=20) + 1x1 conv block + global max pool + 3 FC.
// B=8, N=2048. Feature buffer X: (B, N, XS) rows, columns [pts(3)|f1(64)|f2(64)|f3(64)|f4(128)].
// XS=324 keeps rows 16B-aligned for float4 loads (column 323 is an unused pad).

constexpr int BB = 8;
constexpr int NN = 2048;
constexpr int KK = 20;
constexpr int CT = 323;
constexpr int XS = 324;
constexpr float NEGS = 0.2f;

__device__ __forceinline__ float lrelu(float v) { return v > 0.0f ? v : NEGS * v; }

__device__ __forceinline__ void atomicMaxF(float* addr, float v) {
    if (v >= 0.0f) atomicMax((int*)addr, __float_as_int(v));
    else           atomicMin((unsigned int*)addr, __float_as_uint(v));
}

// ---- fused prep: weight packs + W5T transpose + gfeat init + transpose/sq0 + X zero-fill -
// Wa4/Wd4 packed layout, per-stage chunk-row base (float4 elems): st0@0, st1@64, st2@1216
// (36 chunks: 34 real + 2 zero-padded so stage-3 NPASS=6 divides evenly), st3@3520.
// Zero-padded chunks + zero-filled X feature columns make pad reads exactly 0*0.
constexpr int WTOT = 9920;
__global__ void k_prep_all(const float* __restrict__ W1, const float* __restrict__ W2,
                           const float* __restrict__ W3, const float* __restrict__ W4,
                           const float* __restrict__ W5, const float* __restrict__ x,
                           float4* __restrict__ Wa4, float4* __restrict__ Wd4,
                           float* __restrict__ W5T, float* __restrict__ gfeat,
                           float* __restrict__ X, float* __restrict__ sq) {
    int j = blockIdx.x * blockDim.x + threadIdx.x;
    if (j < WTOT) {
        int base, Cout, C;
        const float* W;
        if (j < 64)        { base = 0;    Cout = 64;  C = 3;   W = W1; }
        else if (j < 1216) { base = 64;   Cout = 64;  C = 67;  W = W2; }
        else if (j < 3520) { base = 1216; Cout = 64;  C = 131; W = W3; }
        else               { base = 3520; Cout = 128; C = 195; W = W4; }
        int local = j - base;
        int chunk = local / Cout, o = local % Cout;
        float wa[4], wd[4];
#pragma unroll
        for (int i = 0; i < 4; ++i) {
            int c = 4 * chunk + i;
            if (c < C) {
                wa[i] = W[(size_t)o * 2 * C + c];
                wd[i] = W[(size_t)o * 2 * C + C + c] - wa[i];
            } else { wa[i] = 0.f; wd[i] = 0.f; }
        }
        Wa4[j] = make_float4(wa[0], wa[1], wa[2], wa[3]);
        Wd4[j] = make_float4(wd[0], wd[1], wd[2], wd[3]);
    } else if (j < WTOT + XS * 1024) {
        int t = j - WTOT;
        int c = t / 1024, o = t % 1024;
        W5T[t] = (c < CT) ? W5[(size_t)o * CT + c] : 0.f;   // row 323 zeroed
    } else if (j < WTOT + XS * 1024 + BB * 1024) {
        gfeat[j - WTOT - XS * 1024] = -INFINITY;
    } else if (j < WTOT + XS * 1024 + BB * 1024 + BB * NN) {
        int i = j - WTOT - XS * 1024 - BB * 1024;            // b*NN + n
        int b = i >> 11, n = i & 2047;
        const float* xb = x + (size_t)b * 3 * NN;
        float vx = xb[n], vy = xb[NN + n], vz = xb[2 * NN + n];
        float* row = X + (size_t)i * XS;
        row[0] = vx; row[1] = vy; row[2] = vz; row[3] = 0.f;
        sq[i] = vx * vx + vy * vy + vz * vz;
    } else if (j < WTOT + XS * 1024 + BB * 1024 + BB * NN + BB * NN * 80) {
        // zero-fill X feature columns (float4 indices 1..80 of each row; col 3 done above)
        int t = j - (WTOT + XS * 1024 + BB * 1024 + BB * NN);
        int row = t / 80, c4 = 1 + (t - 80 * row);
        ((float4*)X)[(size_t)row * (XS / 4) + c4] = make_float4(0.f, 0.f, 0.f, 0.f);
    }
}

// ---- dist[b][n][m] = max(sq_n + sq_m - 2*dot, 0) — SYMMETRIC: only tiles ti>=tj ----------
// 128x128 tile, 8x8 per thread. Off-diagonal blocks write direct + mirrored (LDS transpose).
constexpr int TM = 128;
__global__ __launch_bounds__(256) void k_dist(const float* __restrict__ X,
                                              const float* __restrict__ sq,
                                              float* __restrict__ dist, int C) {
    int b = blockIdx.z;
    int blk = blockIdx.x;                 // 0..135 -> (ti, tj), ti >= tj
    int ti = (int)((sqrtf(8.0f * blk + 1.0f) - 1.0f) * 0.5f);
    while ((ti + 1) * (ti + 2) / 2 <= blk) ++ti;
    while (ti * (ti + 1) / 2 > blk) --ti;
    int tj = blk - ti * (ti + 1) / 2;
    int m0 = ti * TM;                     // col tile
    int n0 = tj * TM;                     // row tile
    __shared__ float smem[4352];          // 17 KB: staging (16 KB) / transpose T[32][129]
    float* AsB = smem;                    // As[16][TM]
    float* BsB = smem + 2048;             // Bs[16][TM]
    int tid = threadIdx.x;
    int tx = tid & 15;        // cols: m0 + tx + 16*j
    int ty = tid >> 4;        // rows: n0 + ty*8 + i
    float acc[8][8] = {};
    const float* Xb = X + (size_t)b * NN * XS;
    int sr = tid & 127;       // staging row
    int sc0 = (tid >> 7) * 8; // staging channel half (0 or 8)
    for (int c0 = 0; c0 < C; c0 += 16) {
        const float* arow = Xb + (size_t)(n0 + sr) * XS + c0 + sc0;
        const float* brow = Xb + (size_t)(m0 + sr) * XS + c0 + sc0;
        float4 a0 = *(const float4*)(arow);
        float4 a1 = *(const float4*)(arow + 4);
        float4 b0 = *(const float4*)(brow);
        float4 b1 = *(const float4*)(brow + 4);
        float av[8] = {a0.x, a0.y, a0.z, a0.w, a1.x, a1.y, a1.z, a1.w};
        float bv8[8] = {b0.x, b0.y, b0.z, b0.w, b1.x, b1.y, b1.z, b1.w};
#pragma unroll
        for (int i = 0; i < 8; ++i) {
            bool inr = (c0 + sc0 + i) < C;
            AsB[(sc0 + i) * TM + sr] = inr ? av[i] : 0.f;
            BsB[(sc0 + i) * TM + sr] = inr ? bv8[i] : 0.f;
        }
        __syncthreads();
#pragma unroll
        for (int cc = 0; cc < 16; ++cc) {
            float4 a0r = *(const float4*)&AsB[cc * TM + ty * 8];
            float4 a1r = *(const float4*)&AsB[cc * TM + ty * 8 + 4];
            float a[8] = {a0r.x, a0r.y, a0r.z, a0r.w, a1r.x, a1r.y, a1r.z, a1r.w};
            float bv[8];
#pragma unroll
            for (int j = 0; j < 8; ++j) bv[j] = BsB[cc * TM + tx + 16 * j];
#pragma unroll
            for (int i = 0; i < 8; ++i)
#pragma unroll
                for (int j = 0; j < 8; ++j)
                    acc[i][j] = fmaf(a[i], bv[j], acc[i][j]);
        }
        __syncthreads();
    }
    const float* sqb = sq + b * NN;
    float* db = dist + (size_t)b * NN * NN;
    float sm[8];
#pragma unroll
    for (int j = 0; j < 8; ++j) sm[j] = sqb[m0 + tx + 16 * j];
#pragma unroll
    for (int i = 0; i < 8; ++i) {
        int n = n0 + ty * 8 + i;
        float sn = sqb[n];
#pragma unroll
        for (int j = 0; j < 8; ++j) {
            float d = fmaxf(sn + sm[j] - 2.f * acc[i][j], 0.f);
            acc[i][j] = d;                                   // keep for mirror
            db[(size_t)n * NN + m0 + tx + 16 * j] = d;
        }
    }
    if (ti != tj) {
        // mirrored tile: rows m0.., cols n0.. — 4 passes of 32 m-rows via LDS transpose
        float* T = smem;                  // [32][129]
        int r = tid >> 3;                 // 0..31
        int c0 = (tid & 7) * 16;          // 0..112
#pragma unroll
        for (int p = 0; p < 4; ++p) {
            __syncthreads();              // protect staging/previous pass reads
#pragma unroll
            for (int jj = 0; jj < 2; ++jj) {
                int j = 2 * p + jj;       // m_local = 32p + tx + 16jj
#pragma unroll
                for (int i = 0; i < 8; ++i)
                    T[(tx + 16 * jj) * 129 + ty * 8 + i] = acc[i][j];
            }
            __syncthreads();
            float v[16];
#pragma unroll
            for (int k = 0; k < 16; ++k) v[k] = T[r * 129 + c0 + k];
            float* dst = db + (size_t)(m0 + 32 * p + r) * NN + n0 + c0;
#pragma unroll
            for (int k = 0; k < 4; ++k)
                *(float4*)(dst + 4 * k) = make_float4(v[4 * k], v[4 * k + 1],
                                                      v[4 * k + 2], v[4 * k + 3]);
        }
    }
}

// ---- Batcher odd-even mergesort network, N=16, fully unrolled (registers) ----------------
__device__ __forceinline__ void sortnet16(unsigned long long* k) {
#pragma unroll
    for (int p = 1; p < 16; p <<= 1) {
#pragma unroll
        for (int q = p; q >= 1; q >>= 1) {
#pragma unroll
            for (int j = q % p; j + q < 16; j += 2 * q) {
#pragma unroll
                for (int i = 0; i < q; ++i) {
                    int a = j + i, bx = j + i + q;
                    if (bx < 16 && (a / (2 * p)) == (bx / (2 * p))) {
                        unsigned long long ka = k[a], kb = k[bx];
                        bool sw = kb < ka;
                        k[a]  = sw ? kb : ka;
                        k[bx] = sw ? ka : kb;
                    }
                }
            }
        }
    }
}

// ---- top-K smallest per row: key = (bits(d)<<11)|m; ties -> lower m (lax.top_k) ----------
__global__ __launch_bounds__(128) void k_select(const float* __restrict__ dist,
                                                int* __restrict__ idx) {
    int bn = blockIdx.x;   // b*NN + n
    int tid = threadIdx.x;
    int wv = tid >> 6;
    int lane = tid & 63;
    const float* drow = dist + (size_t)bn * NN;
    int m0 = wv * 1024 + lane * 16;
    unsigned long long k[16];
#pragma unroll
    for (int i = 0; i < 4; ++i) {
        float4 v = *(const float4*)(drow + m0 + 4 * i);
        k[4 * i + 0] = ((unsigned long long)__float_as_uint(v.x) << 11) | (unsigned)(m0 + 4 * i + 0);
        k[4 * i + 1] = ((unsigned long long)__float_as_uint(v.y) << 11) | (unsigned)(m0 + 4 * i + 1);
        k[4 * i + 2] = ((unsigned long long)__float_as_uint(v.z) << 11) | (unsigned)(m0 + 4 * i + 2);
        k[4 * i + 3] = ((unsigned long long)__float_as_uint(v.w) << 11) | (unsigned)(m0 + 4 * i + 3);
    }
    sortnet16(k);
    __shared__ unsigned long long wl[2 * KK];
    for (int kk = 0; kk < KK; ++kk) {
        unsigned long long g = k[0];
#pragma unroll
        for (int s = 1; s < 64; s <<= 1) {
            unsigned long long o = (unsigned long long)__shfl_xor((long long)g, s, 64);
            if (o < g) g = o;
        }
        bool win = (k[0] == g);
#pragma unroll
        for (int i = 0; i < 15; ++i) k[i] = win ? k[i + 1] : k[i];
        k[15] = win ? ~0ull : k[15];
        if (lane == 0) wl[wv * KK + kk] = g;
    }
    __syncthreads();
    if (wv == 0) {
        unsigned long long mk = (lane < 2 * KK) ? wl[lane] : ~0ull;
        int* orow = idx + (size_t)bn * KK;
        for (int kk = 0; kk < KK; ++kk) {
            unsigned long long g = mk;
#pragma unroll
            for (int s = 1; s < 64; s <<= 1) {
                unsigned long long o = (unsigned long long)__shfl_xor((long long)g, s, 64);
                if (o < g) g = o;
            }
            if (mk == g) mk = ~0ull;
            if (lane == 0) orow[kk] = (int)(g & 2047u);
        }
    }
}

// ---- EdgeConv: P points/block, MO outputs/thread, NPASS channel passes. ------------------
// R14: kernel is LDS-read-pipe bound (broadcast ds_read_b128 delivers only 16B). LDS read
// instrs per point = 21*(COUT/MO)/64 per chunk, so MO=4 halves them vs MO=2.
// R15: MO=4 at 128-thread blocks collapsed occupancy (18.5%) -> keep NTHR=256 everywhere.
// R16 post-mortem: __launch_bounds__(256,4) hard-capped VGPR at 64 (needs ~108) -> 830 MB
// of spill writes, 415 us. Empirical cap behaves like ~256/arg2 on this toolchain, and
// arg2=2 measured 108 VGPR with zero spill (R1). So: (256,2) — VGPR ~108 allows 4 waves/SIMD
// (16 waves/CU); LDS <=34KB allows >=4 blocks/CU; occupancy ~50% with halved LDS traffic.
// Stage-3 NC4 padded 34->36 (zero weights + zero-filled X columns keep pads exactly 0).
// PSTR pads per-point nbr stride to ==2 mod 8 float4s so the up-to-4 distinct broadcast
// addresses per wave land 8 banks apart (conflict-free).
// Epilogue updates sq[bn] += sum(new channels^2) via width-OS shuffle reduction.
template <int NC4, int COUT, int P, int NPASS, int MO>
__global__ __launch_bounds__(P * COUT / MO, 2)
void k_conv(const float* __restrict__ X, const int* __restrict__ idx,
            const float4* __restrict__ Wa4, const float4* __restrict__ Wd4,
            const float* __restrict__ scale, const float* __restrict__ bias,
            int outoff, float* __restrict__ Xout, float* __restrict__ sq) {
    constexpr int NCP = NC4 / NPASS;      // chunks per pass (exact: 1, 6, 6, 10)
    constexpr int OS = COUT / MO;         // output slots per point (threads per point)
    constexpr int NTHR = P * OS;
    constexpr int PSTR = KK * NCP + (((2 - (KK * NCP) % 8) + 8) % 8);  // ≡2 mod 8
    int bn0 = blockIdx.x * P;             // P consecutive points, same batch
    int b = bn0 >> 11;                    // NN = 2048
    __shared__ float4 ctr4[P * NCP];
    __shared__ float4 nbr4[P * PSTR];
    __shared__ int sIdx[P * KK];
    int tid = threadIdx.x;
    for (int j = tid; j < P * KK; j += NTHR) sIdx[j] = idx[(size_t)bn0 * KK + j];
    __syncthreads();
    int o = tid & (OS - 1);
    int p = tid / OS;
    float bacc[MO];
    float acc[MO][KK];
#pragma unroll
    for (int m = 0; m < MO; ++m) {
        bacc[m] = 0.f;
#pragma unroll
        for (int kk = 0; kk < KK; ++kk) acc[m][kk] = 0.f;
    }
#pragma unroll 1
    for (int q = 0; q < NPASS; ++q) {
        int cbase = q * NCP;              // global chunk base for this pass
        // stage ctr chunks
        for (int j = tid; j < P * NCP; j += NTHR) {
            int pp = j / NCP, c = j - pp * NCP;
            ctr4[j] = *(const float4*)(X + (size_t)(bn0 + pp) * XS + 4 * (cbase + c));
        }
        // stage nbr chunks (padded per-point stride PSTR)
        for (int j = tid; j < P * KK * NCP; j += NTHR) {
            int pk = j / NCP, c = j - pk * NCP;
            int pp = pk / KK, kk = pk - pp * KK;
            nbr4[pp * PSTR + kk * NCP + c] =
                *(const float4*)(X + (size_t)(b * NN + sIdx[pk]) * XS + 4 * (cbase + c));
        }
        __syncthreads();
        const float4* cp = ctr4 + p * NCP;
        const float4* np = nbr4 + p * PSTR;
#pragma unroll 2
        for (int ch = 0; ch < NCP; ++ch) {
            int gch = cbase + ch;
            float4 wa[MO], wd[MO];
#pragma unroll
            for (int m = 0; m < MO; ++m) {
                wa[m] = Wa4[(size_t)gch * COUT + o + m * OS];
                wd[m] = Wd4[(size_t)gch * COUT + o + m * OS];
            }
            float4 cv = cp[ch];
#pragma unroll
            for (int m = 0; m < MO; ++m) {
                bacc[m] = fmaf(cv.x, wd[m].x, bacc[m]);
                bacc[m] = fmaf(cv.y, wd[m].y, bacc[m]);
                bacc[m] = fmaf(cv.z, wd[m].z, bacc[m]);
                bacc[m] = fmaf(cv.w, wd[m].w, bacc[m]);
            }
#pragma unroll
            for (int kk = 0; kk < KK; ++kk) {
                float4 nv = np[kk * NCP + ch];
#pragma unroll
                for (int m = 0; m < MO; ++m) {
                    acc[m][kk] = fmaf(nv.x, wa[m].x, acc[m][kk]);
                    acc[m][kk] = fmaf(nv.y, wa[m].y, acc[m][kk]);
                    acc[m][kk] = fmaf(nv.z, wa[m].z, acc[m][kk]);
                    acc[m][kk] = fmaf(nv.w, wa[m].w, acc[m][kk]);
                }
            }
        }
        if (q + 1 < NPASS) __syncthreads();   // before next pass overwrites LDS
    }
    float* orow = Xout + (size_t)(bn0 + p) * XS + outoff;
    float v = 0.f;
#pragma unroll
    for (int m = 0; m < MO; ++m) {
        float s0 = scale[o + m * OS], bi0 = bias[o + m * OS];
        float mx = -INFINITY;
#pragma unroll
        for (int kk = 0; kk < KK; ++kk)
            mx = fmaxf(mx, lrelu((bacc[m] + acc[m][kk]) * s0 + bi0));
        orow[o + m * OS] = mx;
        v = fmaf(mx, mx, v);
    }
    // fused sq update for next stage: sq += sum over new channels of value^2
#pragma unroll
    for (int s = 1; s < OS; s <<= 1) v += __shfl_xor(v, s, OS);
    if (o == 0) sq[bn0 + p] += v;
}

// ---- block5: g = lrelu((X . W5^T)*s5+b5), atomic max over n into gfeat -------------------
// float4 LDS broadcasts (8 b128 per 128 FMAs, 1:16) instead of scalar b32.
constexpr int RB = 8;
constexpr int X4S = XS / 4;   // 81 float4 per row
__global__ __launch_bounds__(256) void k_stage5(const float* __restrict__ X,
                                                const float* __restrict__ W5T,
                                                const float* __restrict__ s5,
                                                const float* __restrict__ b5,
                                                float* __restrict__ gfeat) {
    int blk = blockIdx.x;
    int b = blk / (NN / RB);
    int n0 = (blk % (NN / RB)) * RB;
    __shared__ float4 rows4[RB][X4S];
    int tid = threadIdx.x;
    const float4* X4 = (const float4*)X;
    for (int j = tid; j < RB * X4S; j += 256) {
        int r = j / X4S, c = j - r * X4S;
        rows4[r][c] = X4[(size_t)(b * NN + n0 + r) * X4S + c];
    }
    __syncthreads();
    const float4* W5T4 = (const float4*)W5T;   // [XS][256] float4 per row
    float acc[RB][4] = {};
    for (int c4 = 0; c4 < X4S; ++c4) {
        float4 w0 = W5T4[(size_t)(4 * c4 + 0) * 256 + tid];
        float4 w1 = W5T4[(size_t)(4 * c4 + 1) * 256 + tid];
        float4 w2 = W5T4[(size_t)(4 * c4 + 2) * 256 + tid];
        float4 w3 = W5T4[(size_t)(4 * c4 + 3) * 256 + tid];
#pragma unroll
        for (int r = 0; r < RB; ++r) {
            float4 a = rows4[r][c4];
            acc[r][0] = fmaf(a.x, w0.x, acc[r][0]);
            acc[r][1] = fmaf(a.x, w0.y, acc[r][1]);
            acc[r][2] = fmaf(a.x, w0.z, acc[r][2]);
            acc[r][3] = fmaf(a.x, w0.w, acc[r][3]);
            acc[r][0] = fmaf(a.y, w1.x, acc[r][0]);
            acc[r][1] = fmaf(a.y, w1.y, acc[r][1]);
            acc[r][2] = fmaf(a.y, w1.z, acc[r][2]);
            acc[r][3] = fmaf(a.y, w1.w, acc[r][3]);
            acc[r][0] = fmaf(a.z, w2.x, acc[r][0]);
            acc[r][1] = fmaf(a.z, w2.y, acc[r][1]);
            acc[r][2] = fmaf(a.z, w2.z, acc[r][2]);
            acc[r][3] = fmaf(a.z, w2.w, acc[r][3]);
            acc[r][0] = fmaf(a.w, w3.x, acc[r][0]);
            acc[r][1] = fmaf(a.w, w3.y, acc[r][1]);
            acc[r][2] = fmaf(a.w, w3.z, acc[r][2]);
            acc[r][3] = fmaf(a.w, w3.w, acc[r][3]);
        }
    }
    int o0 = tid * 4;
#pragma unroll
    for (int i = 0; i < 4; ++i) {
        int o = o0 + i;
        float s = s5[o], bbv = b5[o];
        float mx = -INFINITY;
#pragma unroll
        for (int r = 0; r < RB; ++r) {
            float v = lrelu(acc[r][i] * s + bbv);
            mx = fmaxf(v, mx);
        }
        atomicMaxF(&gfeat[b * 1024 + o], mx);
    }
}

// ---- fused FC head: fc1 -> fc2 -> fc3 per batch row, intermediates in LDS ----------------
__global__ __launch_bounds__(256) void k_fc(const float* __restrict__ gfeat,
                                            const float* __restrict__ fW1, const float* __restrict__ fb1,
                                            const float* __restrict__ fs1, const float* __restrict__ fB1,
                                            const float* __restrict__ fW2, const float* __restrict__ fb2,
                                            const float* __restrict__ fs2, const float* __restrict__ fB2,
                                            const float* __restrict__ fW3, const float* __restrict__ fb3,
                                            float* __restrict__ logits) {
    int b = blockIdx.x;
    __shared__ float g[1024];
    __shared__ float h1s[512];
    __shared__ float h2s[256];
    int tid = threadIdx.x;
    for (int j = tid; j < 1024; j += 256) g[j] = gfeat[b * 1024 + j];
    __syncthreads();
    for (int o = tid; o < 512; o += 256) {
        const float* wr = fW1 + (size_t)o * 1024;
        float acc = 0.f;
        for (int c = 0; c < 1024; ++c) acc = fmaf(g[c], wr[c], acc);
        h1s[o] = lrelu((acc + fb1[o]) * fs1[o] + fB1[o]);
    }
    __syncthreads();
    {
        int o = tid;
        const float* wr = fW2 + (size_t)o * 512;
        float acc = 0.f;
        for (int c = 0; c < 512; ++c) acc = fmaf(h1s[c], wr[c], acc);
        h2s[o] = lrelu((acc + fb2[o]) * fs2[o] + fB2[o]);
    }
    __syncthreads();
    if (tid < 40) {
        const float* wr = fW3 + (size_t)tid * 256;
        float acc = 0.f;
        for (int c = 0; c < 256; ++c) acc = fmaf(h2s[c], wr[c], acc);
        logits[b * 40 + tid] = acc + fb3[tid];
    }
}

extern "C" void kernel_launch(void* const* d_in, const int* in_sizes, int n_in,
                              void* d_out, int out_size, void* d_ws, size_t ws_size,
                              hipStream_t stream) {
    const float* x   = (const float*)d_in[0];
    const float* W1  = (const float*)d_in[1];
    const float* s1  = (const float*)d_in[2];
    const float* b1  = (const float*)d_in[3];
    const float* W2  = (const float*)d_in[4];
    const float* s2  = (const float*)d_in[5];
    const float* b2  = (const float*)d_in[6];
    const float* W3  = (const float*)d_in[7];
    const float* s3  = (const float*)d_in[8];
    const float* b3  = (const float*)d_in[9];
    const float* W4  = (const float*)d_in[10];
    const float* s4  = (const float*)d_in[11];
    const float* b4  = (const float*)d_in[12];
    const float* W5  = (const float*)d_in[13];
    const float* s5  = (const float*)d_in[14];
    const float* b5  = (const float*)d_in[15];
    const float* fW1 = (const float*)d_in[16];
    const float* fb1 = (const float*)d_in[17];
    const float* fs1 = (const float*)d_in[18];
    const float* fB1 = (const float*)d_in[19];
    const float* fW2 = (const float*)d_in[20];
    const float* fb2 = (const float*)d_in[21];
    const float* fs2 = (const float*)d_in[22];
    const float* fB2 = (const float*)d_in[23];
    const float* fW3 = (const float*)d_in[24];
    const float* fb3 = (const float*)d_in[25];

    float* out    = (float*)d_out;
    float* logits = out;          // 8*40
    float* gfeat  = out + 320;    // 8*1024

    char* ws = (char*)d_ws;
    size_t off = 0;
    auto alloc = [&](size_t bytes) -> void* {
        void* p = ws + off;
        off += (bytes + 255) & ~(size_t)255;
        return p;
    };
    float* X    = (float*)alloc((size_t)BB * NN * XS * 4);      // 21.2 MB
    float* sq   = (float*)alloc((size_t)BB * NN * 4);
    float* dist = (float*)alloc((size_t)BB * NN * NN * 4);      // 134 MB
    int*   idx  = (int*)  alloc((size_t)BB * NN * KK * 4);
    float4* Wa4 = (float4*)alloc((size_t)WTOT * 16);
    float4* Wd4 = (float4*)alloc((size_t)WTOT * 16);
    float* W5T  = (float*)alloc((size_t)XS * 1024 * 4);
    (void)ws_size; (void)in_sizes; (void)n_in; (void)out_size;

    // one-shot prep: weight packs + W5T + gfeat init + transpose/sq0 + X zero-fill
    int prepTot = WTOT + XS * 1024 + BB * 1024 + BB * NN + BB * NN * 80;
    k_prep_all<<<(prepTot + 255) / 256, 256, 0, stream>>>(W1, W2, W3, W4, W5, x,
                                                          Wa4, Wd4, W5T, gfeat, X, sq);

    const int Cs[4]    = {3, 67, 131, 195};
    const int offs[4]  = {3, 67, 131, 195};
    const int WOFF[4]  = {0, 64, 1216, 3520};   // chunk-row base in packed Wa4/Wd4
    const float* ss[4] = {s1, s2, s3, s4};
    const float* bs[4] = {b1, b2, b3, b4};

    constexpr int NT = NN / TM;                 // 16 tiles per dim
    constexpr int NBLK = NT * (NT + 1) / 2;     // 136 lower-triangle tiles
    for (int st = 0; st < 4; ++st) {
        int C = Cs[st];
        dim3 dg(NBLK, 1, BB);
        k_dist<<<dg, 256, 0, stream>>>(X, sq, dist, C);
        k_select<<<BB * NN, 128, 0, stream>>>(dist, idx);
        const float4* wa = Wa4 + WOFF[st];
        const float4* wd = Wd4 + WOFF[st];
        switch (st) {
            case 0: k_conv<1,  64, 16, 1, 4><<<BB * NN / 16, 256, 0, stream>>>(X, idx, wa, wd, ss[st], bs[st], offs[st], X, sq); break;
            case 1: k_conv<18, 64, 16, 3, 4><<<BB * NN / 16, 256, 0, stream>>>(X, idx, wa, wd, ss[st], bs[st], offs[st], X, sq); break;
            case 2: k_conv<36, 64, 16, 6, 4><<<BB * NN / 16, 256, 0, stream>>>(X, idx, wa, wd, ss[st], bs[st], offs[st], X, sq); break;
            case 3: k_conv<50, 128, 8, 5, 4><<<BB * NN / 8,  256, 0, stream>>>(X, idx, wa, wd, ss[st], bs[st], offs[st], X, sq); break;
        }
    }

    k_stage5<<<BB * (NN / RB), 256, 0, stream>>>(X, W5T, s5, b5, gfeat);
    k_fc<<<BB, 256, 0, stream>>>(gfeat, fW1, fb1, fs1, fB1,
                                 fW2, fb2, fs2, fB2, fW3, fb3, logits);
}

// Round 5
// 1443.025 us; speedup vs baseline: 1.3212x; 1.2155x over previous
//
#include <hip/hip_runtime.h>
#include <math.h>

// LDGCNN forward: 4 EdgeConv blocks (knn K=20) + 1x1 conv block + global max pool + 3 FC.
// B=8, N=2048. Feature buffer X: (B, N, XS) rows, columns [pts(3)|f1(64)|f2(64)|f3(64)|f4(128)].
// XS=324 keeps rows 16B-aligned for float4 loads (column 323 is an unused pad).
//
// R17 structural change: EdgeConv is linear in (nbr, ctr) separately:
//   h[n,k,o] = H[idx[n,k],o] + G[n,o],  H = X.Wa^T, G = X.Wd^T  (Wd = Wb - Wa)
// so the per-(n,k) gathered GEMM (R0-R16's k_conv, 305us stage 4, 85% gather-latency
// stall) is replaced by one dense GEMM (k_hg, 20x fewer FLOPs, no gather) + a cache-
// resident gather+max (k_edgemax, H is 8.4MB -> L2/L3).

constexpr int BB = 8;
constexpr int NN = 2048;
constexpr int KK = 20;
constexpr int CT = 323;
constexpr int XS = 324;
constexpr int X4S = XS / 4;   // 81 float4 per row
constexpr float NEGS = 0.2f;

__device__ __forceinline__ float lrelu(float v) { return v > 0.0f ? v : NEGS * v; }

__device__ __forceinline__ void atomicMaxF(float* addr, float v) {
    if (v >= 0.0f) atomicMax((int*)addr, __float_as_int(v));
    else           atomicMin((unsigned int*)addr, __float_as_uint(v));
}

__device__ __forceinline__ void fma4(float4& a, float x, const float4 w) {
    a.x = fmaf(x, w.x, a.x); a.y = fmaf(x, w.y, a.y);
    a.z = fmaf(x, w.z, a.z); a.w = fmaf(x, w.w, a.w);
}

// ---- fused prep: WT packs + W5T transpose + gfeat init + transpose/sq0 + X zero-fill -----
// WT layout per stage: [4*KC4 channel rows][2*COUT floats]: cols [0,COUT)=Wa[o][c],
// [COUT,2COUT)=Wd[o][c]=W[o][C+c]-W[o][c]. Channel rows c>=C zero-padded (X cols beyond the
// written prefix are zero-filled, so pad contributions are exactly 0).
// float4 bases: st1@0 (4x32), st2@128 (68x32), st3@2304 (132x32), st4@6528 (196x64).
constexpr int WTOT = 19072;
__global__ void k_prep_all(const float* __restrict__ W1, const float* __restrict__ W2,
                           const float* __restrict__ W3, const float* __restrict__ W4,
                           const float* __restrict__ W5, const float* __restrict__ x,
                           float4* __restrict__ WT4, float* __restrict__ W5T,
                           float* __restrict__ gfeat, float* __restrict__ X,
                           float* __restrict__ sq) {
    int j = blockIdx.x * blockDim.x + threadIdx.x;
    if (j < WTOT) {
        int base, Cout, C;
        const float* W;
        if (j < 128)       { base = 0;    Cout = 64;  C = 3;   W = W1; }
        else if (j < 2304) { base = 128;  Cout = 64;  C = 67;  W = W2; }
        else if (j < 6528) { base = 2304; Cout = 64;  C = 131; W = W3; }
        else               { base = 6528; Cout = 128; C = 195; W = W4; }
        int W4w = Cout / 2;                 // 2*Cout/4 float4 groups per channel row
        int local = j - base;
        int c = local / W4w, og = local - c * W4w;
        float v[4];
#pragma unroll
        for (int q = 0; q < 4; ++q) {
            int o2 = 4 * og + q;
            if (c >= C) v[q] = 0.f;
            else if (o2 < Cout) v[q] = W[(size_t)o2 * 2 * C + c];
            else {
                int o = o2 - Cout;
                v[q] = W[(size_t)o * 2 * C + C + c] - W[(size_t)o * 2 * C + c];
            }
        }
        WT4[j] = make_float4(v[0], v[1], v[2], v[3]);
    } else if (j < WTOT + XS * 1024) {
        int t = j - WTOT;
        int c = t / 1024, o = t % 1024;
        W5T[t] = (c < CT) ? W5[(size_t)o * CT + c] : 0.f;   // row 323 zeroed
    } else if (j < WTOT + XS * 1024 + BB * 1024) {
        gfeat[j - WTOT - XS * 1024] = -INFINITY;
    } else if (j < WTOT + XS * 1024 + BB * 1024 + BB * NN) {
        int i = j - WTOT - XS * 1024 - BB * 1024;            // b*NN + n
        int b = i >> 11, n = i & 2047;
        const float* xb = x + (size_t)b * 3 * NN;
        float vx = xb[n], vy = xb[NN + n], vz = xb[2 * NN + n];
        float* row = X + (size_t)i * XS;
        row[0] = vx; row[1] = vy; row[2] = vz; row[3] = 0.f;
        sq[i] = vx * vx + vy * vy + vz * vz;
    } else if (j < WTOT + XS * 1024 + BB * 1024 + BB * NN + BB * NN * 80) {
        // zero-fill X feature columns (float4 indices 1..80 of each row; col 3 done above)
        int t = j - (WTOT + XS * 1024 + BB * 1024 + BB * NN);
        int row = t / 80, c4 = 1 + (t - 80 * row);
        ((float4*)X)[(size_t)row * X4S + c4] = make_float4(0.f, 0.f, 0.f, 0.f);
    }
}

// ---- dist[b][n][m] = max(sq_n + sq_m - 2*dot, 0) — SYMMETRIC: only tiles ti>=tj ----------
// 128x128 tile, 8x8 per thread. Off-diagonal blocks write direct + mirrored (LDS transpose).
constexpr int TM = 128;
__global__ __launch_bounds__(256) void k_dist(const float* __restrict__ X,
                                              const float* __restrict__ sq,
                                              float* __restrict__ dist, int C) {
    int b = blockIdx.z;
    int blk = blockIdx.x;                 // 0..135 -> (ti, tj), ti >= tj
    int ti = (int)((sqrtf(8.0f * blk + 1.0f) - 1.0f) * 0.5f);
    while ((ti + 1) * (ti + 2) / 2 <= blk) ++ti;
    while (ti * (ti + 1) / 2 > blk) --ti;
    int tj = blk - ti * (ti + 1) / 2;
    int m0 = ti * TM;                     // col tile
    int n0 = tj * TM;                     // row tile
    __shared__ float smem[4352];          // 17 KB: staging (16 KB) / transpose T[32][129]
    float* AsB = smem;                    // As[16][TM]
    float* BsB = smem + 2048;             // Bs[16][TM]
    int tid = threadIdx.x;
    int tx = tid & 15;        // cols: m0 + tx + 16*j
    int ty = tid >> 4;        // rows: n0 + ty*8 + i
    float acc[8][8] = {};
    const float* Xb = X + (size_t)b * NN * XS;
    int sr = tid & 127;       // staging row
    int sc0 = (tid >> 7) * 8; // staging channel half (0 or 8)
    for (int c0 = 0; c0 < C; c0 += 16) {
        const float* arow = Xb + (size_t)(n0 + sr) * XS + c0 + sc0;
        const float* brow = Xb + (size_t)(m0 + sr) * XS + c0 + sc0;
        float4 a0 = *(const float4*)(arow);
        float4 a1 = *(const float4*)(arow + 4);
        float4 b0 = *(const float4*)(brow);
        float4 b1 = *(const float4*)(brow + 4);
        float av[8] = {a0.x, a0.y, a0.z, a0.w, a1.x, a1.y, a1.z, a1.w};
        float bv8[8] = {b0.x, b0.y, b0.z, b0.w, b1.x, b1.y, b1.z, b1.w};
#pragma unroll
        for (int i = 0; i < 8; ++i) {
            bool inr = (c0 + sc0 + i) < C;
            AsB[(sc0 + i) * TM + sr] = inr ? av[i] : 0.f;
            BsB[(sc0 + i) * TM + sr] = inr ? bv8[i] : 0.f;
        }
        __syncthreads();
#pragma unroll
        for (int cc = 0; cc < 16; ++cc) {
            float4 a0r = *(const float4*)&AsB[cc * TM + ty * 8];
            float4 a1r = *(const float4*)&AsB[cc * TM + ty * 8 + 4];
            float a[8] = {a0r.x, a0r.y, a0r.z, a0r.w, a1r.x, a1r.y, a1r.z, a1r.w};
            float bv[8];
#pragma unroll
            for (int j = 0; j < 8; ++j) bv[j] = BsB[cc * TM + tx + 16 * j];
#pragma unroll
            for (int i = 0; i < 8; ++i)
#pragma unroll
                for (int j = 0; j < 8; ++j)
                    acc[i][j] = fmaf(a[i], bv[j], acc[i][j]);
        }
        __syncthreads();
    }
    const float* sqb = sq + b * NN;
    float* db = dist + (size_t)b * NN * NN;
    float sm[8];
#pragma unroll
    for (int j = 0; j < 8; ++j) sm[j] = sqb[m0 + tx + 16 * j];
#pragma unroll
    for (int i = 0; i < 8; ++i) {
        int n = n0 + ty * 8 + i;
        float sn = sqb[n];
#pragma unroll
        for (int j = 0; j < 8; ++j) {
            float d = fmaxf(sn + sm[j] - 2.f * acc[i][j], 0.f);
            acc[i][j] = d;                                   // keep for mirror
            db[(size_t)n * NN + m0 + tx + 16 * j] = d;
        }
    }
    if (ti != tj) {
        // mirrored tile: rows m0.., cols n0.. — 4 passes of 32 m-rows via LDS transpose
        float* T = smem;                  // [32][129]
        int r = tid >> 3;                 // 0..31
        int c0 = (tid & 7) * 16;          // 0..112
#pragma unroll
        for (int p = 0; p < 4; ++p) {
            __syncthreads();              // protect staging/previous pass reads
#pragma unroll
            for (int jj = 0; jj < 2; ++jj) {
                int j = 2 * p + jj;       // m_local = 32p + tx + 16jj
#pragma unroll
                for (int i = 0; i < 8; ++i)
                    T[(tx + 16 * jj) * 129 + ty * 8 + i] = acc[i][j];
            }
            __syncthreads();
            float v[16];
#pragma unroll
            for (int k = 0; k < 16; ++k) v[k] = T[r * 129 + c0 + k];
            float* dst = db + (size_t)(m0 + 32 * p + r) * NN + n0 + c0;
#pragma unroll
            for (int k = 0; k < 4; ++k)
                *(float4*)(dst + 4 * k) = make_float4(v[4 * k], v[4 * k + 1],
                                                      v[4 * k + 2], v[4 * k + 3]);
        }
    }
}

// ---- Batcher odd-even mergesort network, N=16, fully unrolled (registers) ----------------
__device__ __forceinline__ void sortnet16(unsigned long long* k) {
#pragma unroll
    for (int p = 1; p < 16; p <<= 1) {
#pragma unroll
        for (int q = p; q >= 1; q >>= 1) {
#pragma unroll
            for (int j = q % p; j + q < 16; j += 2 * q) {
#pragma unroll
                for (int i = 0; i < q; ++i) {
                    int a = j + i, bx = j + i + q;
                    if (bx < 16 && (a / (2 * p)) == (bx / (2 * p))) {
                        unsigned long long ka = k[a], kb = k[bx];
                        bool sw = kb < ka;
                        k[a]  = sw ? kb : ka;
                        k[bx] = sw ? ka : kb;
                    }
                }
            }
        }
    }
}

// ---- top-K smallest per row: key = (bits(d)<<11)|m; ties -> lower m (lax.top_k) ----------
__global__ __launch_bounds__(128) void k_select(const float* __restrict__ dist,
                                                int* __restrict__ idx) {
    int bn = blockIdx.x;   // b*NN + n
    int tid = threadIdx.x;
    int wv = tid >> 6;
    int lane = tid & 63;
    const float* drow = dist + (size_t)bn * NN;
    int m0 = wv * 1024 + lane * 16;
    unsigned long long k[16];
#pragma unroll
    for (int i = 0; i < 4; ++i) {
        float4 v = *(const float4*)(drow + m0 + 4 * i);
        k[4 * i + 0] = ((unsigned long long)__float_as_uint(v.x) << 11) | (unsigned)(m0 + 4 * i + 0);
        k[4 * i + 1] = ((unsigned long long)__float_as_uint(v.y) << 11) | (unsigned)(m0 + 4 * i + 1);
        k[4 * i + 2] = ((unsigned long long)__float_as_uint(v.z) << 11) | (unsigned)(m0 + 4 * i + 2);
        k[4 * i + 3] = ((unsigned long long)__float_as_uint(v.w) << 11) | (unsigned)(m0 + 4 * i + 3);
    }
    sortnet16(k);
    __shared__ unsigned long long wl[2 * KK];
    for (int kk = 0; kk < KK; ++kk) {
        unsigned long long g = k[0];
#pragma unroll
        for (int s = 1; s < 64; s <<= 1) {
            unsigned long long o = (unsigned long long)__shfl_xor((long long)g, s, 64);
            if (o < g) g = o;
        }
        bool win = (k[0] == g);
#pragma unroll
        for (int i = 0; i < 15; ++i) k[i] = win ? k[i + 1] : k[i];
        k[15] = win ? ~0ull : k[15];
        if (lane == 0) wl[wv * KK + kk] = g;
    }
    __syncthreads();
    if (wv == 0) {
        unsigned long long mk = (lane < 2 * KK) ? wl[lane] : ~0ull;
        int* orow = idx + (size_t)bn * KK;
        for (int kk = 0; kk < KK; ++kk) {
            unsigned long long g = mk;
#pragma unroll
            for (int s = 1; s < 64; s <<= 1) {
                unsigned long long o = (unsigned long long)__shfl_xor((long long)g, s, 64);
                if (o < g) g = o;
            }
            if (mk == g) mk = ~0ull;
            if (lane == 0) orow[kk] = (int)(g & 2047u);
        }
    }
}

// ---- k_hg: H = X.Wa^T, G = X.Wd^T — dense GEMM, no gather. -------------------------------
// Block: 256 threads, RB2=32 point-rows. Thread owns 4 outputs (og) x RPT rows; X rows
// staged in LDS; weight float4 loads coalesced and L2-resident (WT <= 200KB/stage).
template <int KC4, int COUT>
__global__ __launch_bounds__(256)
void k_hg(const float* __restrict__ X, const float4* __restrict__ WT4,
          float* __restrict__ H, float* __restrict__ G) {
    constexpr int W4 = COUT / 2;            // 2*COUT/4 float4 outputs per channel row
    constexpr int RB2 = 32;
    constexpr int RPT = RB2 * W4 / 256;     // rows per thread (8 for COUT=128, 4 for 64)
    int bn0 = blockIdx.x * RB2;
    __shared__ float4 xs[RB2][KC4];
    int tid = threadIdx.x;
    const float4* X4 = (const float4*)X;
    for (int j = tid; j < RB2 * KC4; j += 256) {
        int r = j / KC4, c = j - r * KC4;
        xs[r][c] = X4[(size_t)(bn0 + r) * X4S + c];
    }
    __syncthreads();
    int og = tid & (W4 - 1);
    int rg = tid / W4;                      // row group
    float4 acc[RPT];
#pragma unroll
    for (int i = 0; i < RPT; ++i) acc[i] = make_float4(0.f, 0.f, 0.f, 0.f);
#pragma unroll 2
    for (int c4 = 0; c4 < KC4; ++c4) {
        float4 w0 = WT4[(size_t)(4 * c4 + 0) * W4 + og];
        float4 w1 = WT4[(size_t)(4 * c4 + 1) * W4 + og];
        float4 w2 = WT4[(size_t)(4 * c4 + 2) * W4 + og];
        float4 w3 = WT4[(size_t)(4 * c4 + 3) * W4 + og];
#pragma unroll
        for (int i = 0; i < RPT; ++i) {
            float4 xv = xs[rg * RPT + i][c4];
            fma4(acc[i], xv.x, w0);
            fma4(acc[i], xv.y, w1);
            fma4(acc[i], xv.z, w2);
            fma4(acc[i], xv.w, w3);
        }
    }
    int o2 = 4 * og;
#pragma unroll
    for (int i = 0; i < RPT; ++i) {
        int bn = bn0 + rg * RPT + i;
        if (o2 < COUT) *(float4*)&H[(size_t)bn * COUT + o2] = acc[i];
        else           *(float4*)&G[(size_t)bn * COUT + (o2 - COUT)] = acc[i];
    }
}

// ---- k_edgemax: X[bn, outoff+o] = max_k lrelu((H[idx[bn,k],o] + G[bn,o])*s+b) ------------
// One wave per point: 20 independent coalesced H-row reads (cache-resident), 3 VALU/elem.
// Epilogue fuses sq[bn] += sum(new channels^2) (full-wave shuffle reduce).
template <int COUT>
__global__ __launch_bounds__(256)
void k_edgemax(const float* __restrict__ H, const float* __restrict__ G,
               const int* __restrict__ idx, const float* __restrict__ scale,
               const float* __restrict__ bias, int outoff,
               float* __restrict__ X, float* __restrict__ sq) {
    constexpr int CPL = COUT / 64;          // cols per lane (1 or 2)
    int wv = threadIdx.x >> 6, lane = threadIdx.x & 63;
    int bn = blockIdx.x * 4 + wv;
    int b = bn >> 11;                       // NN = 2048
    int id = idx[(size_t)bn * KK + (lane < KK ? lane : 0)];
    float gv[CPL], sv[CPL], bv[CPL], mx[CPL];
#pragma unroll
    for (int q = 0; q < CPL; ++q) {
        int o = lane + 64 * q;
        gv[q] = G[(size_t)bn * COUT + o];
        sv[q] = scale[o];
        bv[q] = bias[o];
        mx[q] = -INFINITY;
    }
#pragma unroll
    for (int k = 0; k < KK; ++k) {
        int m = __shfl(id, k, 64);
        const float* hrow = H + (size_t)(b * NN + m) * COUT;
#pragma unroll
        for (int q = 0; q < CPL; ++q) {
            float v = hrow[lane + 64 * q] + gv[q];
            mx[q] = fmaxf(mx[q], lrelu(v * sv[q] + bv[q]));
        }
    }
    float* orow = X + (size_t)bn * XS + outoff;
    float v = 0.f;
#pragma unroll
    for (int q = 0; q < CPL; ++q) {
        orow[lane + 64 * q] = mx[q];
        v = fmaf(mx[q], mx[q], v);
    }
#pragma unroll
    for (int s = 1; s < 64; s <<= 1) v += __shfl_xor(v, s, 64);
    if (lane == 0) sq[bn] += v;
}

// ---- block5: g = lrelu((X . W5^T)*s5+b5), atomic max over n into gfeat -------------------
// float4 LDS broadcasts (8 b128 per 128 FMAs, 1:16) instead of scalar b32.
constexpr int RB = 8;
__global__ __launch_bounds__(256) void k_stage5(const float* __restrict__ X,
                                                const float* __restrict__ W5T,
                                                const float* __restrict__ s5,
                                                const float* __restrict__ b5,
                                                float* __restrict__ gfeat) {
    int blk = blockIdx.x;
    int b = blk / (NN / RB);
    int n0 = (blk % (NN / RB)) * RB;
    __shared__ float4 rows4[RB][X4S];
    int tid = threadIdx.x;
    const float4* X4 = (const float4*)X;
    for (int j = tid; j < RB * X4S; j += 256) {
        int r = j / X4S, c = j - r * X4S;
        rows4[r][c] = X4[(size_t)(b * NN + n0 + r) * X4S + c];
    }
    __syncthreads();
    const float4* W5T4 = (const float4*)W5T;   // [XS][256] float4 per row
    float acc[RB][4] = {};
    for (int c4 = 0; c4 < X4S; ++c4) {
        float4 w0 = W5T4[(size_t)(4 * c4 + 0) * 256 + tid];
        float4 w1 = W5T4[(size_t)(4 * c4 + 1) * 256 + tid];
        float4 w2 = W5T4[(size_t)(4 * c4 + 2) * 256 + tid];
        float4 w3 = W5T4[(size_t)(4 * c4 + 3) * 256 + tid];
#pragma unroll
        for (int r = 0; r < RB; ++r) {
            float4 a = rows4[r][c4];
            acc[r][0] = fmaf(a.x, w0.x, acc[r][0]);
            acc[r][1] = fmaf(a.x, w0.y, acc[r][1]);
            acc[r][2] = fmaf(a.x, w0.z, acc[r][2]);
            acc[r][3] = fmaf(a.x, w0.w, acc[r][3]);
            acc[r][0] = fmaf(a.y, w1.x, acc[r][0]);
            acc[r][1] = fmaf(a.y, w1.y, acc[r][1]);
            acc[r][2] = fmaf(a.y, w1.z, acc[r][2]);
            acc[r][3] = fmaf(a.y, w1.w, acc[r][3]);
            acc[r][0] = fmaf(a.z, w2.x, acc[r][0]);
            acc[r][1] = fmaf(a.z, w2.y, acc[r][1]);
            acc[r][2] = fmaf(a.z, w2.z, acc[r][2]);
            acc[r][3] = fmaf(a.z, w2.w, acc[r][3]);
            acc[r][0] = fmaf(a.w, w3.x, acc[r][0]);
            acc[r][1] = fmaf(a.w, w3.y, acc[r][1]);
            acc[r][2] = fmaf(a.w, w3.z, acc[r][2]);
            acc[r][3] = fmaf(a.w, w3.w, acc[r][3]);
        }
    }
    int o0 = tid * 4;
#pragma unroll
    for (int i = 0; i < 4; ++i) {
        int o = o0 + i;
        float s = s5[o], bbv = b5[o];
        float mx = -INFINITY;
#pragma unroll
        for (int r = 0; r < RB; ++r) {
            float v = lrelu(acc[r][i] * s + bbv);
            mx = fmaxf(v, mx);
        }
        atomicMaxF(&gfeat[b * 1024 + o], mx);
    }
}

// ---- fused FC head: fc1 -> fc2 -> fc3 per batch row, intermediates in LDS ----------------
__global__ __launch_bounds__(256) void k_fc(const float* __restrict__ gfeat,
                                            const float* __restrict__ fW1, const float* __restrict__ fb1,
                                            const float* __restrict__ fs1, const float* __restrict__ fB1,
                                            const float* __restrict__ fW2, const float* __restrict__ fb2,
                                            const float* __restrict__ fs2, const float* __restrict__ fB2,
                                            const float* __restrict__ fW3, const float* __restrict__ fb3,
                                            float* __restrict__ logits) {
    int b = blockIdx.x;
    __shared__ float g[1024];
    __shared__ float h1s[512];
    __shared__ float h2s[256];
    int tid = threadIdx.x;
    for (int j = tid; j < 1024; j += 256) g[j] = gfeat[b * 1024 + j];
    __syncthreads();
    for (int o = tid; o < 512; o += 256) {
        const float* wr = fW1 + (size_t)o * 1024;
        float acc = 0.f;
        for (int c = 0; c < 1024; ++c) acc = fmaf(g[c], wr[c], acc);
        h1s[o] = lrelu((acc + fb1[o]) * fs1[o] + fB1[o]);
    }
    __syncthreads();
    {
        int o = tid;
        const float* wr = fW2 + (size_t)o * 512;
        float acc = 0.f;
        for (int c = 0; c < 512; ++c) acc = fmaf(h1s[c], wr[c], acc);
        h2s[o] = lrelu((acc + fb2[o]) * fs2[o] + fB2[o]);
    }
    __syncthreads();
    if (tid < 40) {
        const float* wr = fW3 + (size_t)tid * 256;
        float acc = 0.f;
        for (int c = 0; c < 256; ++c) acc = fmaf(h2s[c], wr[c], acc);
        logits[b * 40 + tid] = acc + fb3[tid];
    }
}

extern "C" void kernel_launch(void* const* d_in, const int* in_sizes, int n_in,
                              void* d_out, int out_size, void* d_ws, size_t ws_size,
                              hipStream_t stream) {
    const float* x   = (const float*)d_in[0];
    const float* W1  = (const float*)d_in[1];
    const float* s1  = (const float*)d_in[2];
    const float* b1  = (const float*)d_in[3];
    const float* W2  = (const float*)d_in[4];
    const float* s2  = (const float*)d_in[5];
    const float* b2  = (const float*)d_in[6];
    const float* W3  = (const float*)d_in[7];
    const float* s3  = (const float*)d_in[8];
    const float* b3  = (const float*)d_in[9];
    const float* W4  = (const float*)d_in[10];
    const float* s4  = (const float*)d_in[11];
    const float* b4  = (const float*)d_in[12];
    const float* W5  = (const float*)d_in[13];
    const float* s5  = (const float*)d_in[14];
    const float* b5  = (const float*)d_in[15];
    const float* fW1 = (const float*)d_in[16];
    const float* fb1 = (const float*)d_in[17];
    const float* fs1 = (const float*)d_in[18];
    const float* fB1 = (const float*)d_in[19];
    const float* fW2 = (const float*)d_in[20];
    const float* fb2 = (const float*)d_in[21];
    const float* fs2 = (const float*)d_in[22];
    const float* fB2 = (const float*)d_in[23];
    const float* fW3 = (const float*)d_in[24];
    const float* fb3 = (const float*)d_in[25];

    float* out    = (float*)d_out;
    float* logits = out;          // 8*40
    float* gfeat  = out + 320;    // 8*1024

    char* ws = (char*)d_ws;
    size_t off = 0;
    auto alloc = [&](size_t bytes) -> void* {
        void* p = ws + off;
        off += (bytes + 255) & ~(size_t)255;
        return p;
    };
    float* X    = (float*)alloc((size_t)BB * NN * XS * 4);      // 21.2 MB
    float* sq   = (float*)alloc((size_t)BB * NN * 4);
    float* dist = (float*)alloc((size_t)BB * NN * NN * 4);      // 134 MB
    int*   idx  = (int*)  alloc((size_t)BB * NN * KK * 4);
    float4* WT4 = (float4*)alloc((size_t)WTOT * 16);            // 305 KB
    float* H    = (float*)alloc((size_t)BB * NN * 128 * 4);     // 8.4 MB
    float* G    = (float*)alloc((size_t)BB * NN * 128 * 4);     // 8.4 MB
    float* W5T  = (float*)alloc((size_t)XS * 1024 * 4);
    (void)ws_size; (void)in_sizes; (void)n_in; (void)out_size;

    // one-shot prep: WT packs + W5T + gfeat init + transpose/sq0 + X zero-fill
    int prepTot = WTOT + XS * 1024 + BB * 1024 + BB * NN + BB * NN * 80;
    k_prep_all<<<(prepTot + 255) / 256, 256, 0, stream>>>(W1, W2, W3, W4, W5, x,
                                                          WT4, W5T, gfeat, X, sq);

    const int Cs[4]    = {3, 67, 131, 195};
    const int offs[4]  = {3, 67, 131, 195};
    const int WOFF[4]  = {0, 128, 2304, 6528};  // channel-row base in packed WT4
    const float* ss[4] = {s1, s2, s3, s4};
    const float* bs[4] = {b1, b2, b3, b4};

    constexpr int NT = NN / TM;                 // 16 tiles per dim
    constexpr int NBLK = NT * (NT + 1) / 2;     // 136 lower-triangle tiles
    for (int st = 0; st < 4; ++st) {
        int C = Cs[st];
        dim3 dg(NBLK, 1, BB);
        k_dist<<<dg, 256, 0, stream>>>(X, sq, dist, C);
        k_select<<<BB * NN, 128, 0, stream>>>(dist, idx);
        const float4* wt = WT4 + WOFF[st];
        switch (st) {
            case 0:
                k_hg<1, 64><<<BB * NN / 32, 256, 0, stream>>>(X, wt, H, G);
                k_edgemax<64><<<BB * NN / 4, 256, 0, stream>>>(H, G, idx, ss[st], bs[st], offs[st], X, sq);
                break;
            case 1:
                k_hg<17, 64><<<BB * NN / 32, 256, 0, stream>>>(X, wt, H, G);
                k_edgemax<64><<<BB * NN / 4, 256, 0, stream>>>(H, G, idx, ss[st], bs[st], offs[st], X, sq);
                break;
            case 2:
                k_hg<33, 64><<<BB * NN / 32, 256, 0, stream>>>(X, wt, H, G);
                k_edgemax<64><<<BB * NN / 4, 256, 0, stream>>>(H, G, idx, ss[st], bs[st], offs[st], X, sq);
                break;
            case 3:
                k_hg<49, 128><<<BB * NN / 32, 256, 0, stream>>>(X, wt, H, G);
                k_edgemax<128><<<BB * NN / 4, 256, 0, stream>>>(H, G, idx, ss[st], bs[st], offs[st], X, sq);
                break;
        }
    }

    k_stage5<<<BB * (NN / RB), 256, 0, stream>>>(X, W5T, s5, b5, gfeat);
    k_fc<<<BB, 256, 0, stream>>>(gfeat, fW1, fb1, fs1, fB1,
                                 fW2, fb2, fs2, fB2, fW3, fb3, logits);
}

// Round 6
// 1353.091 us; speedup vs baseline: 1.4090x; 1.0665x over previous
//
#include <hip/hip_runtime.h>
#include <math.h>

// LDGCNN forward: 4 EdgeConv blocks (knn K=20) + 1x1 conv block + global max pool + 3 FC.
// B=8, N=2048. Feature buffer X: (B, N, XS) rows, columns [pts(3)|f1(64)|f2(64)|f3(64)|f4(128)].
// XS=324 keeps rows 16B-aligned for float4 loads (column 323 is an unused pad).
//
// R17 structural change: EdgeConv is linear in (nbr, ctr) separately:
//   h[n,k,o] = H[idx[n,k],o] + G[n,o],  H = X.Wa^T, G = X.Wd^T  (Wd = Wb - Wa)
// so the per-(n,k) gathered GEMM is replaced by one dense GEMM (k_hg, 20x fewer FLOPs,
// no gather) + a cache-resident gather+max (k_edgemax, H is 8.4MB -> L2/L3).
// R19 (this round): k_stage5 RB 8->32, 512 thr — each block re-reads the whole 1.33MB W5T,
// so W5T L2 traffic scales 1/RB: 2.7GB -> 680MB. FMA floor is 69us; was 216us measured.

constexpr int BB = 8;
constexpr int NN = 2048;
constexpr int KK = 20;
constexpr int CT = 323;
constexpr int XS = 324;
constexpr int X4S = XS / 4;   // 81 float4 per row
constexpr float NEGS = 0.2f;

__device__ __forceinline__ float lrelu(float v) { return v > 0.0f ? v : NEGS * v; }

__device__ __forceinline__ void atomicMaxF(float* addr, float v) {
    if (v >= 0.0f) atomicMax((int*)addr, __float_as_int(v));
    else           atomicMin((unsigned int*)addr, __float_as_uint(v));
}

__device__ __forceinline__ void fma4(float4& a, float x, const float4 w) {
    a.x = fmaf(x, w.x, a.x); a.y = fmaf(x, w.y, a.y);
    a.z = fmaf(x, w.z, a.z); a.w = fmaf(x, w.w, a.w);
}

// ---- fused prep: WT packs + W5T transpose + gfeat init + transpose/sq0 + X zero-fill -----
// WT layout per stage: [4*KC4 channel rows][2*COUT floats]: cols [0,COUT)=Wa[o][c],
// [COUT,2COUT)=Wd[o][c]=W[o][C+c]-W[o][c]. Channel rows c>=C zero-padded (X cols beyond the
// written prefix are zero-filled, so pad contributions are exactly 0).
// float4 bases: st1@0 (4x32), st2@128 (68x32), st3@2304 (132x32), st4@6528 (196x64).
constexpr int WTOT = 19072;
__global__ void k_prep_all(const float* __restrict__ W1, const float* __restrict__ W2,
                           const float* __restrict__ W3, const float* __restrict__ W4,
                           const float* __restrict__ W5, const float* __restrict__ x,
                           float4* __restrict__ WT4, float* __restrict__ W5T,
                           float* __restrict__ gfeat, float* __restrict__ X,
                           float* __restrict__ sq) {
    int j = blockIdx.x * blockDim.x + threadIdx.x;
    if (j < WTOT) {
        int base, Cout, C;
        const float* W;
        if (j < 128)       { base = 0;    Cout = 64;  C = 3;   W = W1; }
        else if (j < 2304) { base = 128;  Cout = 64;  C = 67;  W = W2; }
        else if (j < 6528) { base = 2304; Cout = 64;  C = 131; W = W3; }
        else               { base = 6528; Cout = 128; C = 195; W = W4; }
        int W4w = Cout / 2;                 // 2*Cout/4 float4 groups per channel row
        int local = j - base;
        int c = local / W4w, og = local - c * W4w;
        float v[4];
#pragma unroll
        for (int q = 0; q < 4; ++q) {
            int o2 = 4 * og + q;
            if (c >= C) v[q] = 0.f;
            else if (o2 < Cout) v[q] = W[(size_t)o2 * 2 * C + c];
            else {
                int o = o2 - Cout;
                v[q] = W[(size_t)o * 2 * C + C + c] - W[(size_t)o * 2 * C + c];
            }
        }
        WT4[j] = make_float4(v[0], v[1], v[2], v[3]);
    } else if (j < WTOT + XS * 1024) {
        int t = j - WTOT;
        int c = t / 1024, o = t % 1024;
        W5T[t] = (c < CT) ? W5[(size_t)o * CT + c] : 0.f;   // row 323 zeroed
    } else if (j < WTOT + XS * 1024 + BB * 1024) {
        gfeat[j - WTOT - XS * 1024] = -INFINITY;
    } else if (j < WTOT + XS * 1024 + BB * 1024 + BB * NN) {
        int i = j - WTOT - XS * 1024 - BB * 1024;            // b*NN + n
        int b = i >> 11, n = i & 2047;
        const float* xb = x + (size_t)b * 3 * NN;
        float vx = xb[n], vy = xb[NN + n], vz = xb[2 * NN + n];
        float* row = X + (size_t)i * XS;
        row[0] = vx; row[1] = vy; row[2] = vz; row[3] = 0.f;
        sq[i] = vx * vx + vy * vy + vz * vz;
    } else if (j < WTOT + XS * 1024 + BB * 1024 + BB * NN + BB * NN * 80) {
        // zero-fill X feature columns (float4 indices 1..80 of each row; col 3 done above)
        int t = j - (WTOT + XS * 1024 + BB * 1024 + BB * NN);
        int row = t / 80, c4 = 1 + (t - 80 * row);
        ((float4*)X)[(size_t)row * X4S + c4] = make_float4(0.f, 0.f, 0.f, 0.f);
    }
}

// ---- dist[b][n][m] = max(sq_n + sq_m - 2*dot, 0) — SYMMETRIC: only tiles ti>=tj ----------
// 128x128 tile, 8x8 per thread. Off-diagonal blocks write direct + mirrored (LDS transpose).
constexpr int TM = 128;
__global__ __launch_bounds__(256) void k_dist(const float* __restrict__ X,
                                              const float* __restrict__ sq,
                                              float* __restrict__ dist, int C) {
    int b = blockIdx.z;
    int blk = blockIdx.x;                 // 0..135 -> (ti, tj), ti >= tj
    int ti = (int)((sqrtf(8.0f * blk + 1.0f) - 1.0f) * 0.5f);
    while ((ti + 1) * (ti + 2) / 2 <= blk) ++ti;
    while (ti * (ti + 1) / 2 > blk) --ti;
    int tj = blk - ti * (ti + 1) / 2;
    int m0 = ti * TM;                     // col tile
    int n0 = tj * TM;                     // row tile
    __shared__ float smem[4352];          // 17 KB: staging (16 KB) / transpose T[32][129]
    float* AsB = smem;                    // As[16][TM]
    float* BsB = smem + 2048;             // Bs[16][TM]
    int tid = threadIdx.x;
    int tx = tid & 15;        // cols: m0 + tx + 16*j
    int ty = tid >> 4;        // rows: n0 + ty*8 + i
    float acc[8][8] = {};
    const float* Xb = X + (size_t)b * NN * XS;
    int sr = tid & 127;       // staging row
    int sc0 = (tid >> 7) * 8; // staging channel half (0 or 8)
    for (int c0 = 0; c0 < C; c0 += 16) {
        const float* arow = Xb + (size_t)(n0 + sr) * XS + c0 + sc0;
        const float* brow = Xb + (size_t)(m0 + sr) * XS + c0 + sc0;
        float4 a0 = *(const float4*)(arow);
        float4 a1 = *(const float4*)(arow + 4);
        float4 b0 = *(const float4*)(brow);
        float4 b1 = *(const float4*)(brow + 4);
        float av[8] = {a0.x, a0.y, a0.z, a0.w, a1.x, a1.y, a1.z, a1.w};
        float bv8[8] = {b0.x, b0.y, b0.z, b0.w, b1.x, b1.y, b1.z, b1.w};
#pragma unroll
        for (int i = 0; i < 8; ++i) {
            bool inr = (c0 + sc0 + i) < C;
            AsB[(sc0 + i) * TM + sr] = inr ? av[i] : 0.f;
            BsB[(sc0 + i) * TM + sr] = inr ? bv8[i] : 0.f;
        }
        __syncthreads();
#pragma unroll
        for (int cc = 0; cc < 16; ++cc) {
            float4 a0r = *(const float4*)&AsB[cc * TM + ty * 8];
            float4 a1r = *(const float4*)&AsB[cc * TM + ty * 8 + 4];
            float a[8] = {a0r.x, a0r.y, a0r.z, a0r.w, a1r.x, a1r.y, a1r.z, a1r.w};
            float bv[8];
#pragma unroll
            for (int j = 0; j < 8; ++j) bv[j] = BsB[cc * TM + tx + 16 * j];
#pragma unroll
            for (int i = 0; i < 8; ++i)
#pragma unroll
                for (int j = 0; j < 8; ++j)
                    acc[i][j] = fmaf(a[i], bv[j], acc[i][j]);
        }
        __syncthreads();
    }
    const float* sqb = sq + b * NN;
    float* db = dist + (size_t)b * NN * NN;
    float sm[8];
#pragma unroll
    for (int j = 0; j < 8; ++j) sm[j] = sqb[m0 + tx + 16 * j];
#pragma unroll
    for (int i = 0; i < 8; ++i) {
        int n = n0 + ty * 8 + i;
        float sn = sqb[n];
#pragma unroll
        for (int j = 0; j < 8; ++j) {
            float d = fmaxf(sn + sm[j] - 2.f * acc[i][j], 0.f);
            acc[i][j] = d;                                   // keep for mirror
            db[(size_t)n * NN + m0 + tx + 16 * j] = d;
        }
    }
    if (ti != tj) {
        // mirrored tile: rows m0.., cols n0.. — 4 passes of 32 m-rows via LDS transpose
        float* T = smem;                  // [32][129]
        int r = tid >> 3;                 // 0..31
        int c0 = (tid & 7) * 16;          // 0..112
#pragma unroll
        for (int p = 0; p < 4; ++p) {
            __syncthreads();              // protect staging/previous pass reads
#pragma unroll
            for (int jj = 0; jj < 2; ++jj) {
                int j = 2 * p + jj;       // m_local = 32p + tx + 16jj
#pragma unroll
                for (int i = 0; i < 8; ++i)
                    T[(tx + 16 * jj) * 129 + ty * 8 + i] = acc[i][j];
            }
            __syncthreads();
            float v[16];
#pragma unroll
            for (int k = 0; k < 16; ++k) v[k] = T[r * 129 + c0 + k];
            float* dst = db + (size_t)(m0 + 32 * p + r) * NN + n0 + c0;
#pragma unroll
            for (int k = 0; k < 4; ++k)
                *(float4*)(dst + 4 * k) = make_float4(v[4 * k], v[4 * k + 1],
                                                      v[4 * k + 2], v[4 * k + 3]);
        }
    }
}

// ---- Batcher odd-even mergesort network, N=16, fully unrolled (registers) ----------------
__device__ __forceinline__ void sortnet16(unsigned long long* k) {
#pragma unroll
    for (int p = 1; p < 16; p <<= 1) {
#pragma unroll
        for (int q = p; q >= 1; q >>= 1) {
#pragma unroll
            for (int j = q % p; j + q < 16; j += 2 * q) {
#pragma unroll
                for (int i = 0; i < q; ++i) {
                    int a = j + i, bx = j + i + q;
                    if (bx < 16 && (a / (2 * p)) == (bx / (2 * p))) {
                        unsigned long long ka = k[a], kb = k[bx];
                        bool sw = kb < ka;
                        k[a]  = sw ? kb : ka;
                        k[bx] = sw ? ka : kb;
                    }
                }
            }
        }
    }
}

// ---- top-K smallest per row: key = (bits(d)<<11)|m; ties -> lower m (lax.top_k) ----------
__global__ __launch_bounds__(128) void k_select(const float* __restrict__ dist,
                                                int* __restrict__ idx) {
    int bn = blockIdx.x;   // b*NN + n
    int tid = threadIdx.x;
    int wv = tid >> 6;
    int lane = tid & 63;
    const float* drow = dist + (size_t)bn * NN;
    int m0 = wv * 1024 + lane * 16;
    unsigned long long k[16];
#pragma unroll
    for (int i = 0; i < 4; ++i) {
        float4 v = *(const float4*)(drow + m0 + 4 * i);
        k[4 * i + 0] = ((unsigned long long)__float_as_uint(v.x) << 11) | (unsigned)(m0 + 4 * i + 0);
        k[4 * i + 1] = ((unsigned long long)__float_as_uint(v.y) << 11) | (unsigned)(m0 + 4 * i + 1);
        k[4 * i + 2] = ((unsigned long long)__float_as_uint(v.z) << 11) | (unsigned)(m0 + 4 * i + 2);
        k[4 * i + 3] = ((unsigned long long)__float_as_uint(v.w) << 11) | (unsigned)(m0 + 4 * i + 3);
    }
    sortnet16(k);
    __shared__ unsigned long long wl[2 * KK];
    for (int kk = 0; kk < KK; ++kk) {
        unsigned long long g = k[0];
#pragma unroll
        for (int s = 1; s < 64; s <<= 1) {
            unsigned long long o = (unsigned long long)__shfl_xor((long long)g, s, 64);
            if (o < g) g = o;
        }
        bool win = (k[0] == g);
#pragma unroll
        for (int i = 0; i < 15; ++i) k[i] = win ? k[i + 1] : k[i];
        k[15] = win ? ~0ull : k[15];
        if (lane == 0) wl[wv * KK + kk] = g;
    }
    __syncthreads();
    if (wv == 0) {
        unsigned long long mk = (lane < 2 * KK) ? wl[lane] : ~0ull;
        int* orow = idx + (size_t)bn * KK;
        for (int kk = 0; kk < KK; ++kk) {
            unsigned long long g = mk;
#pragma unroll
            for (int s = 1; s < 64; s <<= 1) {
                unsigned long long o = (unsigned long long)__shfl_xor((long long)g, s, 64);
                if (o < g) g = o;
            }
            if (mk == g) mk = ~0ull;
            if (lane == 0) orow[kk] = (int)(g & 2047u);
        }
    }
}

// ---- k_hg: H = X.Wa^T, G = X.Wd^T — dense GEMM, no gather. -------------------------------
// Block: 256 threads, RB2=32 point-rows. Thread owns 4 outputs (og) x RPT rows; X rows
// staged in LDS; weight float4 loads coalesced and L2-resident (WT <= 200KB/stage).
template <int KC4, int COUT>
__global__ __launch_bounds__(256)
void k_hg(const float* __restrict__ X, const float4* __restrict__ WT4,
          float* __restrict__ H, float* __restrict__ G) {
    constexpr int W4 = COUT / 2;            // 2*COUT/4 float4 outputs per channel row
    constexpr int RB2 = 32;
    constexpr int RPT = RB2 * W4 / 256;     // rows per thread (8 for COUT=128, 4 for 64)
    int bn0 = blockIdx.x * RB2;
    __shared__ float4 xs[RB2][KC4];
    int tid = threadIdx.x;
    const float4* X4 = (const float4*)X;
    for (int j = tid; j < RB2 * KC4; j += 256) {
        int r = j / KC4, c = j - r * KC4;
        xs[r][c] = X4[(size_t)(bn0 + r) * X4S + c];
    }
    __syncthreads();
    int og = tid & (W4 - 1);
    int rg = tid / W4;                      // row group
    float4 acc[RPT];
#pragma unroll
    for (int i = 0; i < RPT; ++i) acc[i] = make_float4(0.f, 0.f, 0.f, 0.f);
#pragma unroll 2
    for (int c4 = 0; c4 < KC4; ++c4) {
        float4 w0 = WT4[(size_t)(4 * c4 + 0) * W4 + og];
        float4 w1 = WT4[(size_t)(4 * c4 + 1) * W4 + og];
        float4 w2 = WT4[(size_t)(4 * c4 + 2) * W4 + og];
        float4 w3 = WT4[(size_t)(4 * c4 + 3) * W4 + og];
#pragma unroll
        for (int i = 0; i < RPT; ++i) {
            float4 xv = xs[rg * RPT + i][c4];
            fma4(acc[i], xv.x, w0);
            fma4(acc[i], xv.y, w1);
            fma4(acc[i], xv.z, w2);
            fma4(acc[i], xv.w, w3);
        }
    }
    int o2 = 4 * og;
#pragma unroll
    for (int i = 0; i < RPT; ++i) {
        int bn = bn0 + rg * RPT + i;
        if (o2 < COUT) *(float4*)&H[(size_t)bn * COUT + o2] = acc[i];
        else           *(float4*)&G[(size_t)bn * COUT + (o2 - COUT)] = acc[i];
    }
}

// ---- k_edgemax: X[bn, outoff+o] = max_k lrelu((H[idx[bn,k],o] + G[bn,o])*s+b) ------------
// One wave per point: 20 independent coalesced H-row reads (cache-resident), 3 VALU/elem.
// Epilogue fuses sq[bn] += sum(new channels^2) (full-wave shuffle reduce).
template <int COUT>
__global__ __launch_bounds__(256)
void k_edgemax(const float* __restrict__ H, const float* __restrict__ G,
               const int* __restrict__ idx, const float* __restrict__ scale,
               const float* __restrict__ bias, int outoff,
               float* __restrict__ X, float* __restrict__ sq) {
    constexpr int CPL = COUT / 64;          // cols per lane (1 or 2)
    int wv = threadIdx.x >> 6, lane = threadIdx.x & 63;
    int bn = blockIdx.x * 4 + wv;
    int b = bn >> 11;                       // NN = 2048
    int id = idx[(size_t)bn * KK + (lane < KK ? lane : 0)];
    float gv[CPL], sv[CPL], bv[CPL], mx[CPL];
#pragma unroll
    for (int q = 0; q < CPL; ++q) {
        int o = lane + 64 * q;
        gv[q] = G[(size_t)bn * COUT + o];
        sv[q] = scale[o];
        bv[q] = bias[o];
        mx[q] = -INFINITY;
    }
#pragma unroll
    for (int k = 0; k < KK; ++k) {
        int m = __shfl(id, k, 64);
        const float* hrow = H + (size_t)(b * NN + m) * COUT;
#pragma unroll
        for (int q = 0; q < CPL; ++q) {
            float v = hrow[lane + 64 * q] + gv[q];
            mx[q] = fmaxf(mx[q], lrelu(v * sv[q] + bv[q]));
        }
    }
    float* orow = X + (size_t)bn * XS + outoff;
    float v = 0.f;
#pragma unroll
    for (int q = 0; q < CPL; ++q) {
        orow[lane + 64 * q] = mx[q];
        v = fmaf(mx[q], mx[q], v);
    }
#pragma unroll
    for (int s = 1; s < 64; s <<= 1) v += __shfl_xor(v, s, 64);
    if (lane == 0) sq[bn] += v;
}

// ---- block5: g = lrelu((X . W5^T)*s5+b5), atomic max over n into gfeat -------------------
// R19: RB 8->32 rows/block, 512 threads (2 row-groups x 256 output-slots). Each block reads
// the full 1.33MB W5T once, so total W5T L2 traffic = (16384/RB)*1.33MB: 2.7GB @ RB=8 ->
// 680MB @ RB=32. acc[16][4]=64 VGPR (~110 total, no min-waves bound per R2 lesson).
// LDS 41.5KB -> 2 blocks/CU. rg is wave-uniform -> rows4 reads stay broadcasts.
constexpr int RB = 32;
__global__ __launch_bounds__(512) void k_stage5(const float* __restrict__ X,
                                                const float* __restrict__ W5T,
                                                const float* __restrict__ s5,
                                                const float* __restrict__ b5,
                                                float* __restrict__ gfeat) {
    int blk = blockIdx.x;
    int b = blk / (NN / RB);
    int n0 = (blk % (NN / RB)) * RB;
    __shared__ float4 rows4[RB][X4S];     // 41472 B
    int tid = threadIdx.x;
    const float4* X4 = (const float4*)X;
    for (int j = tid; j < RB * X4S; j += 512) {
        int r = j / X4S, c = j - r * X4S;
        rows4[r][c] = X4[(size_t)(b * NN + n0 + r) * X4S + c];
    }
    __syncthreads();
    const float4* W5T4 = (const float4*)W5T;   // [XS][256] float4 per row
    int og = tid & 255;                   // output float4 slot (4 outputs)
    int r0 = (tid >> 8) * 16;             // row group: rows r0..r0+15 (wave-uniform)
    float acc[16][4] = {};
    for (int c4 = 0; c4 < X4S; ++c4) {
        float4 w0 = W5T4[(size_t)(4 * c4 + 0) * 256 + og];
        float4 w1 = W5T4[(size_t)(4 * c4 + 1) * 256 + og];
        float4 w2 = W5T4[(size_t)(4 * c4 + 2) * 256 + og];
        float4 w3 = W5T4[(size_t)(4 * c4 + 3) * 256 + og];
#pragma unroll
        for (int r = 0; r < 16; ++r) {
            float4 a = rows4[r0 + r][c4];
            acc[r][0] = fmaf(a.x, w0.x, acc[r][0]);
            acc[r][1] = fmaf(a.x, w0.y, acc[r][1]);
            acc[r][2] = fmaf(a.x, w0.z, acc[r][2]);
            acc[r][3] = fmaf(a.x, w0.w, acc[r][3]);
            acc[r][0] = fmaf(a.y, w1.x, acc[r][0]);
            acc[r][1] = fmaf(a.y, w1.y, acc[r][1]);
            acc[r][2] = fmaf(a.y, w1.z, acc[r][2]);
            acc[r][3] = fmaf(a.y, w1.w, acc[r][3]);
            acc[r][0] = fmaf(a.z, w2.x, acc[r][0]);
            acc[r][1] = fmaf(a.z, w2.y, acc[r][1]);
            acc[r][2] = fmaf(a.z, w2.z, acc[r][2]);
            acc[r][3] = fmaf(a.z, w2.w, acc[r][3]);
            acc[r][0] = fmaf(a.w, w3.x, acc[r][0]);
            acc[r][1] = fmaf(a.w, w3.y, acc[r][1]);
            acc[r][2] = fmaf(a.w, w3.z, acc[r][2]);
            acc[r][3] = fmaf(a.w, w3.w, acc[r][3]);
        }
    }
    int o0 = og * 4;
#pragma unroll
    for (int i = 0; i < 4; ++i) {
        int o = o0 + i;
        float s = s5[o], bbv = b5[o];
        float mx = -INFINITY;
#pragma unroll
        for (int r = 0; r < 16; ++r) {
            float v = lrelu(acc[r][i] * s + bbv);
            mx = fmaxf(v, mx);
        }
        atomicMaxF(&gfeat[b * 1024 + o], mx);
    }
}

// ---- fused FC head: fc1 -> fc2 -> fc3 per batch row, intermediates in LDS ----------------
__global__ __launch_bounds__(256) void k_fc(const float* __restrict__ gfeat,
                                            const float* __restrict__ fW1, const float* __restrict__ fb1,
                                            const float* __restrict__ fs1, const float* __restrict__ fB1,
                                            const float* __restrict__ fW2, const float* __restrict__ fb2,
                                            const float* __restrict__ fs2, const float* __restrict__ fB2,
                                            const float* __restrict__ fW3, const float* __restrict__ fb3,
                                            float* __restrict__ logits) {
    int b = blockIdx.x;
    __shared__ float g[1024];
    __shared__ float h1s[512];
    __shared__ float h2s[256];
    int tid = threadIdx.x;
    for (int j = tid; j < 1024; j += 256) g[j] = gfeat[b * 1024 + j];
    __syncthreads();
    for (int o = tid; o < 512; o += 256) {
        const float* wr = fW1 + (size_t)o * 1024;
        float acc = 0.f;
        for (int c = 0; c < 1024; ++c) acc = fmaf(g[c], wr[c], acc);
        h1s[o] = lrelu((acc + fb1[o]) * fs1[o] + fB1[o]);
    }
    __syncthreads();
    {
        int o = tid;
        const float* wr = fW2 + (size_t)o * 512;
        float acc = 0.f;
        for (int c = 0; c < 512; ++c) acc = fmaf(h1s[c], wr[c], acc);
        h2s[o] = lrelu((acc + fb2[o]) * fs2[o] + fB2[o]);
    }
    __syncthreads();
    if (tid < 40) {
        const float* wr = fW3 + (size_t)tid * 256;
        float acc = 0.f;
        for (int c = 0; c < 256; ++c) acc = fmaf(h2s[c], wr[c], acc);
        logits[b * 40 + tid] = acc + fb3[tid];
    }
}

extern "C" void kernel_launch(void* const* d_in, const int* in_sizes, int n_in,
                              void* d_out, int out_size, void* d_ws, size_t ws_size,
                              hipStream_t stream) {
    const float* x   = (const float*)d_in[0];
    const float* W1  = (const float*)d_in[1];
    const float* s1  = (const float*)d_in[2];
    const float* b1  = (const float*)d_in[3];
    const float* W2  = (const float*)d_in[4];
    const float* s2  = (const float*)d_in[5];
    const float* b2  = (const float*)d_in[6];
    const float* W3  = (const float*)d_in[7];
    const float* s3  = (const float*)d_in[8];
    const float* b3  = (const float*)d_in[9];
    const float* W4  = (const float*)d_in[10];
    const float* s4  = (const float*)d_in[11];
    const float* b4  = (const float*)d_in[12];
    const float* W5  = (const float*)d_in[13];
    const float* s5  = (const float*)d_in[14];
    const float* b5  = (const float*)d_in[15];
    const float* fW1 = (const float*)d_in[16];
    const float* fb1 = (const float*)d_in[17];
    const float* fs1 = (const float*)d_in[18];
    const float* fB1 = (const float*)d_in[19];
    const float* fW2 = (const float*)d_in[20];
    const float* fb2 = (const float*)d_in[21];
    const float* fs2 = (const float*)d_in[22];
    const float* fB2 = (const float*)d_in[23];
    const float* fW3 = (const float*)d_in[24];
    const float* fb3 = (const float*)d_in[25];

    float* out    = (float*)d_out;
    float* logits = out;          // 8*40
    float* gfeat  = out + 320;    // 8*1024

    char* ws = (char*)d_ws;
    size_t off = 0;
    auto alloc = [&](size_t bytes) -> void* {
        void* p = ws + off;
        off += (bytes + 255) & ~(size_t)255;
        return p;
    };
    float* X    = (float*)alloc((size_t)BB * NN * XS * 4);      // 21.2 MB
    float* sq   = (float*)alloc((size_t)BB * NN * 4);
    float* dist = (float*)alloc((size_t)BB * NN * NN * 4);      // 134 MB
    int*   idx  = (int*)  alloc((size_t)BB * NN * KK * 4);
    float4* WT4 = (float4*)alloc((size_t)WTOT * 16);            // 305 KB
    float* H    = (float*)alloc((size_t)BB * NN * 128 * 4);     // 8.4 MB
    float* G    = (float*)alloc((size_t)BB * NN * 128 * 4);     // 8.4 MB
    float* W5T  = (float*)alloc((size_t)XS * 1024 * 4);
    (void)ws_size; (void)in_sizes; (void)n_in; (void)out_size;

    // one-shot prep: WT packs + W5T + gfeat init + transpose/sq0 + X zero-fill
    int prepTot = WTOT + XS * 1024 + BB * 1024 + BB * NN + BB * NN * 80;
    k_prep_all<<<(prepTot + 255) / 256, 256, 0, stream>>>(W1, W2, W3, W4, W5, x,
                                                          WT4, W5T, gfeat, X, sq);

    const int Cs[4]    = {3, 67, 131, 195};
    const int offs[4]  = {3, 67, 131, 195};
    const int WOFF[4]  = {0, 128, 2304, 6528};  // channel-row base in packed WT4
    const float* ss[4] = {s1, s2, s3, s4};
    const float* bs[4] = {b1, b2, b3, b4};

    constexpr int NT = NN / TM;                 // 16 tiles per dim
    constexpr int NBLK = NT * (NT + 1) / 2;     // 136 lower-triangle tiles
    for (int st = 0; st < 4; ++st) {
        int C = Cs[st];
        dim3 dg(NBLK, 1, BB);
        k_dist<<<dg, 256, 0, stream>>>(X, sq, dist, C);
        k_select<<<BB * NN, 128, 0, stream>>>(dist, idx);
        const float4* wt = WT4 + WOFF[st];
        switch (st) {
            case 0:
                k_hg<1, 64><<<BB * NN / 32, 256, 0, stream>>>(X, wt, H, G);
                k_edgemax<64><<<BB * NN / 4, 256, 0, stream>>>(H, G, idx, ss[st], bs[st], offs[st], X, sq);
                break;
            case 1:
                k_hg<17, 64><<<BB * NN / 32, 256, 0, stream>>>(X, wt, H, G);
                k_edgemax<64><<<BB * NN / 4, 256, 0, stream>>>(H, G, idx, ss[st], bs[st], offs[st], X, sq);
                break;
            case 2:
                k_hg<33, 64><<<BB * NN / 32, 256, 0, stream>>>(X, wt, H, G);
                k_edgemax<64><<<BB * NN / 4, 256, 0, stream>>>(H, G, idx, ss[st], bs[st], offs[st], X, sq);
                break;
            case 3:
                k_hg<49, 128><<<BB * NN / 32, 256, 0, stream>>>(X, wt, H, G);
                k_edgemax<128><<<BB * NN / 4, 256, 0, stream>>>(H, G, idx, ss[st], bs[st], offs[st], X, sq);
                break;
        }
    }

    k_stage5<<<BB * (NN / RB), 512, 0, stream>>>(X, W5T, s5, b5, gfeat);
    k_fc<<<BB, 256, 0, stream>>>(gfeat, fW1, fb1, fs1, fB1,
                                 fW2, fb2, fs2, fB2, fW3, fb3, logits);
}